// Round 1
// baseline (1153.753 us; speedup 1.0000x reference)
//
#include <hip/hip_runtime.h>
#include <math.h>

#define VOCAB 32000
#define E_DIM 512
#define H_DIM 1024
#define S_LEN 50
#define B_SZ 64
#define T_LEN 10
#define H3 (3 * H_DIM)
#define D2H (2 * H_DIM)

// ---------------------------------------------------------------------------
// Generic copy
// ---------------------------------------------------------------------------
__global__ void copy_f32(const float* __restrict__ src, float* __restrict__ dst, int n) {
    int i = blockIdx.x * blockDim.x + threadIdx.x;
    if (i < n) dst[i] = src[i];
}

// ---------------------------------------------------------------------------
// Embedding gather: X[t*B + b, :] = emb[dec_in(b,t), :]
// dec_in(b,0) = SOS(0); dec_in(b,t) = target[b, t-1]
// ---------------------------------------------------------------------------
__global__ void embed_gather(const int* __restrict__ target,
                             const float* __restrict__ emb,
                             float* __restrict__ X) {
    int m = blockIdx.x;           // t*B + b
    int t = m / B_SZ, b = m % B_SZ;
    int idx = (t == 0) ? 0 : target[b * T_LEN + (t - 1)];
    const float* src = emb + (size_t)idx * E_DIM;
    float* dst = X + (size_t)m * E_DIM;
    for (int e = threadIdx.x; e < E_DIM; e += blockDim.x) dst[e] = src[e];
}

// ---------------------------------------------------------------------------
// keys[b*S + s, d] = enc_out[s, b, d]   ([S,B,2H] -> [B*S, 2H])
// ---------------------------------------------------------------------------
__global__ void keys_gather(const float* __restrict__ enc_out, float* __restrict__ keys) {
    int bs = blockIdx.x;
    int b = bs / S_LEN, s = bs % S_LEN;
    const float* src = enc_out + ((size_t)s * B_SZ + b) * D2H;
    float* dst = keys + (size_t)bs * D2H;
    for (int d = threadIdx.x; d < D2H; d += blockDim.x) dst[d] = src[d];
}

// ---------------------------------------------------------------------------
// Tiled fp32 GEMM: C[M,N] = A[M,K] @ W[N,K]^T + bias[N]
// 64x64 tile, 256 threads (16x16), 4x4 per thread, BK=16.
// LDS stride 68 -> worst 2-way bank alias (free on gfx950).
// Requires M%64==0, N%64==0, K%16==0 (true for all call sites here).
// ---------------------------------------------------------------------------
__global__ __launch_bounds__(256) void gemm_nt(const float* __restrict__ A,
                                               const float* __restrict__ W,
                                               const float* __restrict__ bias,
                                               float* __restrict__ C,
                                               int M, int N, int K) {
    __shared__ float As[16][68];   // [k][m]
    __shared__ float Bs[16][68];   // [k][n]
    const int tid = threadIdx.x;
    const int tx = tid % 16, ty = tid / 16;
    const int m0 = blockIdx.y * 64, n0 = blockIdx.x * 64;
    const int lk = tid % 16;       // k lane for loads
    const int lr = tid / 16;       // row lane for loads (16 rows / pass)

    float acc[4][4] = {};

    for (int k0 = 0; k0 < K; k0 += 16) {
#pragma unroll
        for (int p = 0; p < 4; ++p) {
            int m = lr + p * 16;
            As[lk][m] = A[(size_t)(m0 + m) * K + k0 + lk];
        }
#pragma unroll
        for (int p = 0; p < 4; ++p) {
            int n = lr + p * 16;
            Bs[lk][n] = W[(size_t)(n0 + n) * K + k0 + lk];
        }
        __syncthreads();
#pragma unroll
        for (int kk = 0; kk < 16; ++kk) {
            float a[4], b[4];
            *(float4*)a = *(const float4*)&As[kk][ty * 4];
            *(float4*)b = *(const float4*)&Bs[kk][tx * 4];
#pragma unroll
            for (int i = 0; i < 4; ++i)
#pragma unroll
                for (int j = 0; j < 4; ++j)
                    acc[i][j] += a[i] * b[j];
        }
        __syncthreads();
    }

#pragma unroll
    for (int i = 0; i < 4; ++i) {
        int m = m0 + ty * 4 + i;
        int n = n0 + tx * 4;
        float4 v;
        v.x = acc[i][0] + bias[n + 0];
        v.y = acc[i][1] + bias[n + 1];
        v.z = acc[i][2] + bias[n + 2];
        v.w = acc[i][3] + bias[n + 3];
        *(float4*)&C[(size_t)m * N + n] = v;
    }
}

// ---------------------------------------------------------------------------
// GRU gates (pointwise, after GI and GH GEMMs)
// ---------------------------------------------------------------------------
__global__ void gru_gates(const float* __restrict__ GI, const float* __restrict__ GH,
                          float* __restrict__ h, float* __restrict__ hs, int t) {
    int i = blockIdx.x * blockDim.x + threadIdx.x;   // b*H + j
    if (i >= B_SZ * H_DIM) return;
    int b = i / H_DIM, j = i % H_DIM;
    const float* gi = GI + (size_t)(t * B_SZ + b) * H3;
    const float* gh = GH + (size_t)b * H3;
    float ir = gi[j], iz = gi[j + H_DIM], in = gi[j + 2 * H_DIM];
    float hr = gh[j], hz = gh[j + H_DIM], hn = gh[j + 2 * H_DIM];
    float r = 1.f / (1.f + expf(-(ir + hr)));
    float z = 1.f / (1.f + expf(-(iz + hz)));
    float n = tanhf(in + r * hn);
    float hv = h[i];
    float hnew = (1.f - z) * n + z * hv;
    h[i] = hnew;
    hs[(size_t)t * B_SZ * H_DIM + i] = hnew;
}

// ---------------------------------------------------------------------------
// Additive-attention scores + softmax over S.
// Block per (t*B + b); 4 waves; wave w handles s = w, w+4, ...
// score(s) = sum_h tanh(wq[h] + uk[b,s,h]) * va_w[h] + va_b
// ---------------------------------------------------------------------------
__global__ __launch_bounds__(256) void attn_scores(const float* __restrict__ WQ,
                                                   const float* __restrict__ UK,
                                                   const float* __restrict__ va_w,
                                                   const float* __restrict__ va_b,
                                                   float* __restrict__ weights) {
    __shared__ float wq_s[H_DIM];
    __shared__ float va_s[H_DIM];
    __shared__ float sc[S_LEN];
    int tb = blockIdx.x;         // t*B + b
    int b = tb % B_SZ;
    int tid = threadIdx.x;
    for (int h = tid; h < H_DIM; h += 256) {
        wq_s[h] = WQ[(size_t)tb * H_DIM + h];
        va_s[h] = va_w[h];
    }
    __syncthreads();
    int wave = tid / 64, lane = tid % 64;
    for (int s = wave; s < S_LEN; s += 4) {
        const float* uk = UK + ((size_t)b * S_LEN + s) * H_DIM;
        float acc = 0.f;
#pragma unroll
        for (int i = 0; i < H_DIM / 64; ++i) {
            int h = i * 64 + lane;
            acc += tanhf(wq_s[h] + uk[h]) * va_s[h];
        }
        for (int off = 32; off > 0; off >>= 1) acc += __shfl_down(acc, off);
        if (lane == 0) sc[s] = acc + va_b[0];
    }
    __syncthreads();
    if (tid < 64) {
        float v = (tid < S_LEN) ? sc[tid] : -INFINITY;
        float m = v;
        for (int off = 32; off > 0; off >>= 1) m = fmaxf(m, __shfl_down(m, off));
        m = __shfl(m, 0);
        float e = (tid < S_LEN) ? expf(v - m) : 0.f;
        float sum = e;
        for (int off = 32; off > 0; off >>= 1) sum += __shfl_down(sum, off);
        sum = __shfl(sum, 0);
        if (tid < S_LEN) weights[(size_t)tb * S_LEN + tid] = e / sum;
    }
}

// ---------------------------------------------------------------------------
// context[b,t,:] = sum_s weights[t,b,s] * keys[b,s,:]; then log_softmax over 2H.
// Block per (b*T + t), 256 threads, 8 d's per thread.
// ---------------------------------------------------------------------------
__global__ __launch_bounds__(256) void ctx_logsoftmax(const float* __restrict__ weights,
                                                      const float* __restrict__ keys,
                                                      float* __restrict__ out) {
    __shared__ float w_s[S_LEN];
    __shared__ float wred[4];
    __shared__ float sred[4];
    int bt = blockIdx.x;        // b*T + t
    int b = bt / T_LEN, t = bt % T_LEN;
    int tid = threadIdx.x;
    if (tid < S_LEN) w_s[tid] = weights[((size_t)t * B_SZ + b) * S_LEN + tid];
    __syncthreads();

    float c[8];
#pragma unroll
    for (int i = 0; i < 8; ++i) c[i] = 0.f;
    const float* kb = keys + (size_t)b * S_LEN * D2H;
    for (int s = 0; s < S_LEN; ++s) {
        float ws = w_s[s];
        const float* kr = kb + (size_t)s * D2H;
#pragma unroll
        for (int i = 0; i < 8; ++i) c[i] += ws * kr[i * 256 + tid];
    }

    int wave = tid / 64, lane = tid % 64;
    // block max
    float m = c[0];
#pragma unroll
    for (int i = 1; i < 8; ++i) m = fmaxf(m, c[i]);
    for (int off = 32; off > 0; off >>= 1) m = fmaxf(m, __shfl_down(m, off));
    if (lane == 0) wred[wave] = m;
    __syncthreads();
    if (tid == 0) wred[0] = fmaxf(fmaxf(wred[0], wred[1]), fmaxf(wred[2], wred[3]));
    __syncthreads();
    m = wred[0];
    // block sum of exp
    float sum = 0.f;
#pragma unroll
    for (int i = 0; i < 8; ++i) sum += expf(c[i] - m);
    for (int off = 32; off > 0; off >>= 1) sum += __shfl_down(sum, off);
    if (lane == 0) sred[wave] = sum;
    __syncthreads();
    if (tid == 0) sred[0] = sred[0] + sred[1] + sred[2] + sred[3];
    __syncthreads();
    float lse = m + logf(sred[0]);

    float* o = out + (size_t)bt * D2H;
#pragma unroll
    for (int i = 0; i < 8; ++i) o[i * 256 + tid] = c[i] - lse;
}

// ---------------------------------------------------------------------------
extern "C" void kernel_launch(void* const* d_in, const int* in_sizes, int n_in,
                              void* d_out, int out_size, void* d_ws, size_t ws_size,
                              hipStream_t stream) {
    const float* enc_out = (const float*)d_in[0];
    const float* hidden  = (const float*)d_in[1];
    const int*   target  = (const int*)d_in[2];
    const float* emb     = (const float*)d_in[3];
    const float* w_ih    = (const float*)d_in[4];
    const float* w_hh    = (const float*)d_in[5];
    const float* b_ih    = (const float*)d_in[6];
    const float* b_hh    = (const float*)d_in[7];
    const float* wa_w    = (const float*)d_in[8];
    const float* wa_b    = (const float*)d_in[9];
    const float* ua_w    = (const float*)d_in[10];
    const float* ua_b    = (const float*)d_in[11];
    const float* va_w    = (const float*)d_in[12];
    const float* va_b    = (const float*)d_in[13];
    float* out = (float*)d_out;

    // workspace carve (floats)
    float* ws   = (float*)d_ws;
    float* X    = ws;                          // 640*512
    float* keys = X + 640 * 512;               // 3200*2048
    float* GI   = keys + 3200 * 2048;          // 640*3072
    float* GH   = GI + 640 * 3072;             // 64*3072
    float* hbuf = GH + 64 * 3072;              // 64*1024
    float* hs   = hbuf + 64 * 1024;            // 640*1024
    float* UK   = hs + 640 * 1024;             // 3200*1024
    float* WQ   = UK + 3200 * 1024;            // 640*1024
    float* wts  = WQ + 640 * 1024;             // 640*50

    const int TB = T_LEN * B_SZ;               // 640

    // h0
    copy_f32<<<(B_SZ * H_DIM + 255) / 256, 256, 0, stream>>>(hidden, hbuf, B_SZ * H_DIM);
    // gathers
    embed_gather<<<TB, 256, 0, stream>>>(target, emb, X);
    keys_gather<<<B_SZ * S_LEN, 256, 0, stream>>>(enc_out, keys);

    // GI = X @ w_ih^T + b_ih   [640, 3072], K=512
    gemm_nt<<<dim3(H3 / 64, TB / 64), 256, 0, stream>>>(X, w_ih, b_ih, GI, TB, H3, E_DIM);
    // UK = keys @ ua_w^T + ua_b  [3200, 1024], K=2048
    gemm_nt<<<dim3(H_DIM / 64, (B_SZ * S_LEN) / 64), 256, 0, stream>>>(keys, ua_w, ua_b, UK,
                                                                       B_SZ * S_LEN, H_DIM, D2H);

    // GRU over T steps
    for (int t = 0; t < T_LEN; ++t) {
        // GH = h @ w_hh^T + b_hh  [64, 3072], K=1024
        gemm_nt<<<dim3(H3 / 64, 1), 256, 0, stream>>>(hbuf, w_hh, b_hh, GH, B_SZ, H3, H_DIM);
        gru_gates<<<(B_SZ * H_DIM + 255) / 256, 256, 0, stream>>>(GI, GH, hbuf, hs, t);
    }

    // WQ = hs @ wa_w^T + wa_b  [640, 1024], K=1024
    gemm_nt<<<dim3(H_DIM / 64, TB / 64), 256, 0, stream>>>(hs, wa_w, wa_b, WQ, TB, H_DIM, H_DIM);

    // scores + softmax
    attn_scores<<<TB, 256, 0, stream>>>(WQ, UK, va_w, va_b, wts);

    // context + log_softmax -> out[0 : B*T*2H]
    ctx_logsoftmax<<<B_SZ * T_LEN, 256, 0, stream>>>(wts, keys, out);

    // h_last -> out[B*T*2H : ]
    copy_f32<<<(B_SZ * H_DIM + 255) / 256, 256, 0, stream>>>(hbuf, out + (size_t)B_SZ * T_LEN * D2H,
                                                             B_SZ * H_DIM);
}

// Round 2
// 473.573 us; speedup vs baseline: 2.4363x; 2.4363x over previous
//
#include <hip/hip_runtime.h>
#include <math.h>

#define VOCAB 32000
#define E_DIM 512
#define H_DIM 1024
#define S_LEN 50
#define B_SZ 64
#define T_LEN 10
#define H3 (3 * H_DIM)
#define D2H (2 * H_DIM)

typedef __attribute__((ext_vector_type(8))) short short8;
typedef __attribute__((ext_vector_type(4))) float floatx4;

__device__ __forceinline__ ushort f2b(float f) {
    union { float f; uint32_t u; } x; x.f = f;
    uint32_t r = (x.u + 0x7fff + ((x.u >> 16) & 1)) >> 16;  // RNE
    return (ushort)r;
}

__device__ __forceinline__ float fast_sigmoid(float x) {
    x = fminf(fmaxf(x, -30.f), 30.f);
    return 1.f / (1.f + __expf(-x));
}
__device__ __forceinline__ float fast_tanh(float x) {
    x = fminf(fmaxf(x, -15.f), 15.f);
    float e = __expf(2.f * x);
    return (e - 1.f) / (e + 1.f);
}

// ---------------------------------------------------------------------------
// f32 -> bf16 bulk convert (n must be multiple of 4)
// ---------------------------------------------------------------------------
__global__ void f32_to_bf16_v4(const float* __restrict__ src, ushort* __restrict__ dst, int n4) {
    int i = blockIdx.x * blockDim.x + threadIdx.x;
    if (i >= n4) return;
    float4 v = ((const float4*)src)[i];
    ushort4 o;
    o.x = f2b(v.x); o.y = f2b(v.y); o.z = f2b(v.z); o.w = f2b(v.w);
    ((ushort4*)dst)[i] = o;
}

__global__ void copy_f32(const float* __restrict__ src, float* __restrict__ dst, int n) {
    int i = blockIdx.x * blockDim.x + threadIdx.x;
    if (i < n) dst[i] = src[i];
}

// h0: f32 copy + bf16 copy
__global__ void h0_init(const float* __restrict__ hidden, float* __restrict__ h,
                        ushort* __restrict__ hb) {
    int i = blockIdx.x * blockDim.x + threadIdx.x;
    if (i >= B_SZ * H_DIM) return;
    float v = hidden[i];
    h[i] = v;
    hb[i] = f2b(v);
}

// ---------------------------------------------------------------------------
// Embedding gather -> bf16 X[t*B+b, :]
// ---------------------------------------------------------------------------
__global__ void embed_gather(const int* __restrict__ target,
                             const float* __restrict__ emb,
                             ushort* __restrict__ Xb) {
    int m = blockIdx.x;           // t*B + b
    int t = m / B_SZ, b = m % B_SZ;
    int idx = (t == 0) ? 0 : target[b * T_LEN + (t - 1)];
    const float* src = emb + (size_t)idx * E_DIM;
    ushort* dst = Xb + (size_t)m * E_DIM;
    for (int e = threadIdx.x; e < E_DIM; e += blockDim.x) dst[e] = f2b(src[e]);
}

// ---------------------------------------------------------------------------
// keysb[b*S + s, d] = bf16(enc_out[s, b, d])
// ---------------------------------------------------------------------------
__global__ void keys_gather(const float* __restrict__ enc_out, ushort* __restrict__ keysb) {
    int bs = blockIdx.x;
    int b = bs / S_LEN, s = bs % S_LEN;
    const float* src = enc_out + ((size_t)s * B_SZ + b) * D2H;
    ushort* dst = keysb + (size_t)bs * D2H;
    for (int d = threadIdx.x; d < D2H; d += blockDim.x) dst[d] = f2b(src[d]);
}

// ---------------------------------------------------------------------------
// bf16 MFMA GEMM: C[M,N] = A[M,K] @ W[N,K]^T + bias[N]   (f32 out)
// 256 threads = 4 waves. Tile BM x 128. 16x16x32 bf16 MFMA.
// LDS row stride 40 elements (80B, 16B-aligned, 2-way max alias = free).
// Register-prefetch software pipeline (m93-style).
// Requires M%BM==0, N%128==0, K%32==0.
// ---------------------------------------------------------------------------
template <int BM, int WMW, int WNW>
__global__ __launch_bounds__(256) void gemm_bf16_nt(
    const ushort* __restrict__ A, const ushort* __restrict__ W,
    const float* __restrict__ bias, float* __restrict__ C,
    int M, int N, int K) {
    constexpr int BN = 128;
    constexpr int MI = BM / (16 * WMW);
    constexpr int NI = BN / (16 * WNW);
    constexpr int AC = (BM * 4) / 256;   // A 16B-chunks per thread
    constexpr int BC = (BN * 4) / 256;   // B 16B-chunks per thread

    __shared__ ushort As[BM * 40];
    __shared__ ushort Bs[BN * 40];

    const int tid = threadIdx.x;
    const int w = tid >> 6, lane = tid & 63;
    const int lm = lane & 15, q = lane >> 4;
    const int wm = w / WNW, wn = w % WNW;
    const int m0 = blockIdx.y * BM, n0 = blockIdx.x * BN;

    floatx4 acc[MI][NI];
#pragma unroll
    for (int i = 0; i < MI; ++i)
#pragma unroll
        for (int j = 0; j < NI; ++j)
            acc[i][j] = (floatx4){0.f, 0.f, 0.f, 0.f};

    short8 ar[AC], br[BC];
    auto load_tiles = [&](int k0) {
#pragma unroll
        for (int p = 0; p < AC; ++p) {
            int c = tid + p * 256;
            int row = c >> 2, qq = c & 3;
            ar[p] = *(const short8*)&A[(size_t)(m0 + row) * K + k0 + qq * 8];
        }
#pragma unroll
        for (int p = 0; p < BC; ++p) {
            int c = tid + p * 256;
            int row = c >> 2, qq = c & 3;
            br[p] = *(const short8*)&W[(size_t)(n0 + row) * K + k0 + qq * 8];
        }
    };

    load_tiles(0);
    for (int k0 = 0; k0 < K; k0 += 32) {
#pragma unroll
        for (int p = 0; p < AC; ++p) {
            int c = tid + p * 256;
            int row = c >> 2, qq = c & 3;
            *(short8*)&As[row * 40 + qq * 8] = ar[p];
        }
#pragma unroll
        for (int p = 0; p < BC; ++p) {
            int c = tid + p * 256;
            int row = c >> 2, qq = c & 3;
            *(short8*)&Bs[row * 40 + qq * 8] = br[p];
        }
        __syncthreads();
        if (k0 + 32 < K) load_tiles(k0 + 32);   // prefetch overlaps MFMA below

        short8 af[MI], bfr[NI];
#pragma unroll
        for (int i = 0; i < MI; ++i)
            af[i] = *(const short8*)&As[(wm * MI * 16 + i * 16 + lm) * 40 + q * 8];
#pragma unroll
        for (int j = 0; j < NI; ++j)
            bfr[j] = *(const short8*)&Bs[(wn * NI * 16 + j * 16 + lm) * 40 + q * 8];
#pragma unroll
        for (int i = 0; i < MI; ++i)
#pragma unroll
            for (int j = 0; j < NI; ++j)
                acc[i][j] = __builtin_amdgcn_mfma_f32_16x16x32_bf16(af[i], bfr[j], acc[i][j], 0, 0, 0);
        __syncthreads();
    }

    float bv[NI];
#pragma unroll
    for (int j = 0; j < NI; ++j)
        bv[j] = bias[n0 + wn * NI * 16 + j * 16 + lm];
#pragma unroll
    for (int i = 0; i < MI; ++i) {
#pragma unroll
        for (int j = 0; j < NI; ++j) {
            int col = n0 + wn * NI * 16 + j * 16 + lm;
#pragma unroll
            for (int r = 0; r < 4; ++r) {
                int row = m0 + wm * MI * 16 + i * 16 + q * 4 + r;
                C[(size_t)row * N + col] = acc[i][j][r] + bv[j];
            }
        }
    }
}

// ---------------------------------------------------------------------------
// GRU gates (pointwise, after GI and GH GEMMs)
// ---------------------------------------------------------------------------
__global__ void gru_gates(const float* __restrict__ GI, const float* __restrict__ GH,
                          float* __restrict__ h, ushort* __restrict__ hb,
                          ushort* __restrict__ hsb, int t) {
    int i = blockIdx.x * blockDim.x + threadIdx.x;   // b*H + j
    if (i >= B_SZ * H_DIM) return;
    int b = i / H_DIM, j = i % H_DIM;
    const float* gi = GI + (size_t)(t * B_SZ + b) * H3;
    const float* gh = GH + (size_t)b * H3;
    float ir = gi[j], iz = gi[j + H_DIM], in = gi[j + 2 * H_DIM];
    float hr = gh[j], hz = gh[j + H_DIM], hn = gh[j + 2 * H_DIM];
    float r = fast_sigmoid(ir + hr);
    float z = fast_sigmoid(iz + hz);
    float n = fast_tanh(in + r * hn);
    float hv = h[i];
    float hnew = (1.f - z) * n + z * hv;
    h[i] = hnew;
    ushort hbits = f2b(hnew);
    hb[i] = hbits;
    hsb[(size_t)t * B_SZ * H_DIM + i] = hbits;
}

// ---------------------------------------------------------------------------
// Additive-attention scores + softmax over S.
// ---------------------------------------------------------------------------
__global__ __launch_bounds__(256) void attn_scores(const float* __restrict__ WQ,
                                                   const float* __restrict__ UK,
                                                   const float* __restrict__ va_w,
                                                   const float* __restrict__ va_b,
                                                   float* __restrict__ weights) {
    __shared__ float wq_s[H_DIM];
    __shared__ float va_s[H_DIM];
    __shared__ float sc[S_LEN];
    int tb = blockIdx.x;         // t*B + b
    int b = tb % B_SZ;
    int tid = threadIdx.x;
    for (int h = tid; h < H_DIM; h += 256) {
        wq_s[h] = WQ[(size_t)tb * H_DIM + h];
        va_s[h] = va_w[h];
    }
    __syncthreads();
    int wave = tid / 64, lane = tid % 64;
    for (int s = wave; s < S_LEN; s += 4) {
        const float* uk = UK + ((size_t)b * S_LEN + s) * H_DIM;
        float acc = 0.f;
#pragma unroll
        for (int i = 0; i < H_DIM / 64; ++i) {
            int h = i * 64 + lane;
            acc += fast_tanh(wq_s[h] + uk[h]) * va_s[h];
        }
        for (int off = 32; off > 0; off >>= 1) acc += __shfl_down(acc, off);
        if (lane == 0) sc[s] = acc + va_b[0];
    }
    __syncthreads();
    if (tid < 64) {
        float v = (tid < S_LEN) ? sc[tid] : -INFINITY;
        float m = v;
        for (int off = 32; off > 0; off >>= 1) m = fmaxf(m, __shfl_down(m, off));
        m = __shfl(m, 0);
        float e = (tid < S_LEN) ? __expf(v - m) : 0.f;
        float sum = e;
        for (int off = 32; off > 0; off >>= 1) sum += __shfl_down(sum, off);
        sum = __shfl(sum, 0);
        if (tid < S_LEN) weights[(size_t)tb * S_LEN + tid] = e / sum;
    }
}

// ---------------------------------------------------------------------------
// context + log_softmax; reads enc_out directly (keys[b,s,d] = enc_out[s,b,d])
// ---------------------------------------------------------------------------
__global__ __launch_bounds__(256) void ctx_logsoftmax(const float* __restrict__ weights,
                                                      const float* __restrict__ enc_out,
                                                      float* __restrict__ out) {
    __shared__ float w_s[S_LEN];
    __shared__ float wred[4];
    __shared__ float sred[4];
    int bt = blockIdx.x;        // b*T + t
    int b = bt / T_LEN, t = bt % T_LEN;
    int tid = threadIdx.x;
    if (tid < S_LEN) w_s[tid] = weights[((size_t)t * B_SZ + b) * S_LEN + tid];
    __syncthreads();

    float c[8];
#pragma unroll
    for (int i = 0; i < 8; ++i) c[i] = 0.f;
    for (int s = 0; s < S_LEN; ++s) {
        float ws = w_s[s];
        const float* kr = enc_out + ((size_t)s * B_SZ + b) * D2H;
#pragma unroll
        for (int i = 0; i < 8; ++i) c[i] += ws * kr[i * 256 + tid];
    }

    int wave = tid / 64, lane = tid % 64;
    float m = c[0];
#pragma unroll
    for (int i = 1; i < 8; ++i) m = fmaxf(m, c[i]);
    for (int off = 32; off > 0; off >>= 1) m = fmaxf(m, __shfl_down(m, off));
    if (lane == 0) wred[wave] = m;
    __syncthreads();
    if (tid == 0) wred[0] = fmaxf(fmaxf(wred[0], wred[1]), fmaxf(wred[2], wred[3]));
    __syncthreads();
    m = wred[0];
    float sum = 0.f;
#pragma unroll
    for (int i = 0; i < 8; ++i) sum += __expf(c[i] - m);
    for (int off = 32; off > 0; off >>= 1) sum += __shfl_down(sum, off);
    if (lane == 0) sred[wave] = sum;
    __syncthreads();
    if (tid == 0) sred[0] = sred[0] + sred[1] + sred[2] + sred[3];
    __syncthreads();
    float lse = m + __logf(sred[0]);

    float* o = out + (size_t)bt * D2H;
#pragma unroll
    for (int i = 0; i < 8; ++i) o[i * 256 + tid] = c[i] - lse;
}

// ---------------------------------------------------------------------------
extern "C" void kernel_launch(void* const* d_in, const int* in_sizes, int n_in,
                              void* d_out, int out_size, void* d_ws, size_t ws_size,
                              hipStream_t stream) {
    const float* enc_out = (const float*)d_in[0];
    const float* hidden  = (const float*)d_in[1];
    const int*   target  = (const int*)d_in[2];
    const float* w_ih    = (const float*)d_in[4];
    const float* w_hh    = (const float*)d_in[5];
    const float* b_ih    = (const float*)d_in[6];
    const float* b_hh    = (const float*)d_in[7];
    const float* wa_w    = (const float*)d_in[8];
    const float* wa_b    = (const float*)d_in[9];
    const float* ua_w    = (const float*)d_in[10];
    const float* ua_b    = (const float*)d_in[11];
    const float* va_w    = (const float*)d_in[12];
    const float* va_b    = (const float*)d_in[13];
    const float* emb     = (const float*)d_in[3];
    float* out = (float*)d_out;

    const int TB = T_LEN * B_SZ;               // 640
    const int BS = B_SZ * S_LEN;               // 3200

    // workspace carve (all chunks 16B-aligned)
    char* p = (char*)d_ws;
    float*  GI    = (float*)p;  p += (size_t)TB * H3 * 4;          // 640x3072
    float*  GH    = (float*)p;  p += (size_t)B_SZ * H3 * 4;        // 64x3072
    float*  UK    = (float*)p;  p += (size_t)BS * H_DIM * 4;       // 3200x1024
    float*  WQ    = (float*)p;  p += (size_t)TB * H_DIM * 4;       // 640x1024
    float*  h     = (float*)p;  p += (size_t)B_SZ * H_DIM * 4;     // 64x1024
    float*  wts   = (float*)p;  p += (size_t)TB * S_LEN * 4;       // 640x50
    p = (char*)(((uintptr_t)p + 255) & ~(uintptr_t)255);
    ushort* keysb = (ushort*)p; p += (size_t)BS * D2H * 2;         // 3200x2048
    ushort* Xb    = (ushort*)p; p += (size_t)TB * E_DIM * 2;       // 640x512
    ushort* w_ihb = (ushort*)p; p += (size_t)H3 * E_DIM * 2;       // 3072x512
    ushort* w_hhb = (ushort*)p; p += (size_t)H3 * H_DIM * 2;       // 3072x1024
    ushort* ua_wb = (ushort*)p; p += (size_t)H_DIM * D2H * 2;      // 1024x2048
    ushort* wa_wb = (ushort*)p; p += (size_t)H_DIM * H_DIM * 2;    // 1024x1024
    ushort* hb    = (ushort*)p; p += (size_t)B_SZ * H_DIM * 2;     // 64x1024
    ushort* hsb   = (ushort*)p; p += (size_t)TB * H_DIM * 2;       // 640x1024

    // weight conversions f32 -> bf16
    f32_to_bf16_v4<<<(H3 * E_DIM / 4 + 255) / 256, 256, 0, stream>>>(w_ih, w_ihb, H3 * E_DIM / 4);
    f32_to_bf16_v4<<<(H3 * H_DIM / 4 + 255) / 256, 256, 0, stream>>>(w_hh, w_hhb, H3 * H_DIM / 4);
    f32_to_bf16_v4<<<(H_DIM * D2H / 4 + 255) / 256, 256, 0, stream>>>(ua_w, ua_wb, H_DIM * D2H / 4);
    f32_to_bf16_v4<<<(H_DIM * H_DIM / 4 + 255) / 256, 256, 0, stream>>>(wa_w, wa_wb, H_DIM * H_DIM / 4);

    // gathers + h0
    embed_gather<<<TB, 256, 0, stream>>>(target, emb, Xb);
    keys_gather<<<BS, 256, 0, stream>>>(enc_out, keysb);
    h0_init<<<(B_SZ * H_DIM + 255) / 256, 256, 0, stream>>>(hidden, h, hb);

    // GI = X @ w_ih^T + b_ih   [640, 3072], K=512
    gemm_bf16_nt<128, 2, 2><<<dim3(H3 / 128, TB / 128), 256, 0, stream>>>(
        Xb, w_ihb, b_ih, GI, TB, H3, E_DIM);
    // UK = keys @ ua_w^T + ua_b  [3200, 1024], K=2048
    gemm_bf16_nt<128, 2, 2><<<dim3(H_DIM / 128, BS / 128), 256, 0, stream>>>(
        keysb, ua_wb, ua_b, UK, BS, H_DIM, D2H);

    // GRU over T steps
    for (int t = 0; t < T_LEN; ++t) {
        // GH = h @ w_hh^T + b_hh  [64, 3072], K=1024
        gemm_bf16_nt<64, 1, 4><<<dim3(H3 / 128, 1), 256, 0, stream>>>(
            hb, w_hhb, b_hh, GH, B_SZ, H3, H_DIM);
        gru_gates<<<(B_SZ * H_DIM + 255) / 256, 256, 0, stream>>>(GI, GH, h, hb, hsb, t);
    }

    // WQ = hs @ wa_w^T + wa_b  [640, 1024], K=1024
    gemm_bf16_nt<128, 2, 2><<<dim3(H_DIM / 128, TB / 128), 256, 0, stream>>>(
        hsb, wa_wb, wa_b, WQ, TB, H_DIM, H_DIM);

    // scores + softmax
    attn_scores<<<TB, 256, 0, stream>>>(WQ, UK, va_w, va_b, wts);

    // context + log_softmax -> out[0 : B*T*2H]
    ctx_logsoftmax<<<B_SZ * T_LEN, 256, 0, stream>>>(wts, enc_out, out);

    // h_last -> out[B*T*2H : ]
    copy_f32<<<(B_SZ * H_DIM + 255) / 256, 256, 0, stream>>>(
        h, out + (size_t)B_SZ * T_LEN * D2H, B_SZ * H_DIM);
}

// Round 3
// 370.573 us; speedup vs baseline: 3.1134x; 1.2779x over previous
//
#include <hip/hip_runtime.h>
#include <math.h>

#define VOCAB 32000
#define E_DIM 512
#define H_DIM 1024
#define S_LEN 50
#define B_SZ 64
#define T_LEN 10
#define H3 (3 * H_DIM)
#define D2H (2 * H_DIM)

typedef __attribute__((ext_vector_type(8))) short short8;
typedef __attribute__((ext_vector_type(4))) float floatx4;

__device__ __forceinline__ ushort f2b(float f) {
    union { float f; uint32_t u; } x; x.f = f;
    uint32_t r = (x.u + 0x7fff + ((x.u >> 16) & 1)) >> 16;  // RNE
    return (ushort)r;
}
__device__ __forceinline__ float b2f(ushort u) {
    union { float f; uint32_t u; } x; x.u = ((uint32_t)u) << 16;
    return x.f;
}
__device__ __forceinline__ float fast_sigmoid(float x) {
    x = fminf(fmaxf(x, -30.f), 30.f);
    return 1.f / (1.f + __expf(-x));
}
__device__ __forceinline__ float fast_tanh(float x) {
    x = fminf(fmaxf(x, -15.f), 15.f);
    float e = __expf(2.f * x);
    return (e - 1.f) / (e + 1.f);
}

// ---------------------------------------------------------------------------
// Fused prep: 4 weight converts + keys gather + embed gather + h0 init.
// Block ranges (counts): w_ih 1536 | w_hh 3072 | ua_w 2048 | wa_w 1024 |
//                        keys 3200 | embed 640 | h0 64        = 11584
// ---------------------------------------------------------------------------
#define PB0 1536
#define PB1 (PB0 + 3072)
#define PB2 (PB1 + 2048)
#define PB3 (PB2 + 1024)
#define PB4 (PB3 + 3200)
#define PB5 (PB4 + 640)
#define PB6 (PB5 + 64)

__device__ __forceinline__ void cvt_chunk(const float* src, ushort* dst, int i) {
    float4 v = ((const float4*)src)[i];
    ushort4 o;
    o.x = f2b(v.x); o.y = f2b(v.y); o.z = f2b(v.z); o.w = f2b(v.w);
    ((ushort4*)dst)[i] = o;
}

__global__ __launch_bounds__(256) void prep(
    const float* __restrict__ w_ih, ushort* __restrict__ w_ihb,
    const float* __restrict__ w_hh, ushort* __restrict__ w_hhb,
    const float* __restrict__ ua_w, ushort* __restrict__ ua_wb,
    const float* __restrict__ wa_w, ushort* __restrict__ wa_wb,
    const float* __restrict__ enc_out, ushort* __restrict__ keysb,
    const int* __restrict__ target, const float* __restrict__ emb,
    ushort* __restrict__ Xb,
    const float* __restrict__ hidden, float* __restrict__ h, ushort* __restrict__ hb0) {
    int bid = blockIdx.x, tid = threadIdx.x;
    if (bid < PB0) {
        cvt_chunk(w_ih, w_ihb, bid * 256 + tid);
    } else if (bid < PB1) {
        cvt_chunk(w_hh, w_hhb, (bid - PB0) * 256 + tid);
    } else if (bid < PB2) {
        cvt_chunk(ua_w, ua_wb, (bid - PB1) * 256 + tid);
    } else if (bid < PB3) {
        cvt_chunk(wa_w, wa_wb, (bid - PB2) * 256 + tid);
    } else if (bid < PB4) {
        int bs = bid - PB3;                   // b*S + s
        int b = bs / S_LEN, s = bs % S_LEN;
        const float* src = enc_out + ((size_t)s * B_SZ + b) * D2H;
        ushort* dst = keysb + (size_t)bs * D2H;
#pragma unroll
        for (int p = 0; p < 2; ++p) {
            int i = tid + p * 256;            // float4 index, 512 per row
            float4 v = ((const float4*)src)[i];
            ushort4 o;
            o.x = f2b(v.x); o.y = f2b(v.y); o.z = f2b(v.z); o.w = f2b(v.w);
            ((ushort4*)dst)[i] = o;
        }
    } else if (bid < PB5) {
        int m = bid - PB4;                    // t*B + b
        int t = m / B_SZ, b = m % B_SZ;
        int idx = (t == 0) ? 0 : target[b * T_LEN + (t - 1)];
        if (tid < 128) {                      // 128 float4s per row
            const float* src = emb + (size_t)idx * E_DIM;
            float4 v = ((const float4*)src)[tid];
            ushort4 o;
            o.x = f2b(v.x); o.y = f2b(v.y); o.z = f2b(v.z); o.w = f2b(v.w);
            ((ushort4*)(Xb + (size_t)m * E_DIM))[tid] = o;
        }
    } else {
        int i = (bid - PB5) * 256 + tid;      // float4 index over 64*1024
        float4 v = ((const float4*)hidden)[i];
        ((float4*)h)[i] = v;
        ushort4 o;
        o.x = f2b(v.x); o.y = f2b(v.y); o.z = f2b(v.z); o.w = f2b(v.w);
        ((ushort4*)hb0)[i] = o;
    }
}

// ---------------------------------------------------------------------------
// bf16 MFMA GEMM: C[M,N] = A[M,K] @ W[N,K]^T + bias[N]   (f32 out)
// 1D grid, n-major: n_idx = bid % nbn  -> blocks sharing a W-slice land on
// the same XCD (bid%8) so the slice stays L2-resident.
// ---------------------------------------------------------------------------
template <int BM, int WMW, int WNW>
__global__ __launch_bounds__(256) void gemm_bf16_nt(
    const ushort* __restrict__ A, const ushort* __restrict__ W,
    const float* __restrict__ bias, float* __restrict__ C,
    int M, int N, int K, int nbn) {
    constexpr int BN = 128;
    constexpr int MI = BM / (16 * WMW);
    constexpr int NI = BN / (16 * WNW);
    constexpr int AC = (BM * 4) / 256;
    constexpr int BC = (BN * 4) / 256;

    __shared__ ushort As[BM * 40];
    __shared__ ushort Bs[BN * 40];

    const int tid = threadIdx.x;
    const int w = tid >> 6, lane = tid & 63;
    const int lm = lane & 15, q = lane >> 4;
    const int wm = w / WNW, wn = w % WNW;
    const int bid = blockIdx.x;
    const int n0 = (bid % nbn) * BN;
    const int m0 = (bid / nbn) * BM;

    floatx4 acc[MI][NI];
#pragma unroll
    for (int i = 0; i < MI; ++i)
#pragma unroll
        for (int j = 0; j < NI; ++j)
            acc[i][j] = (floatx4){0.f, 0.f, 0.f, 0.f};

    short8 ar[AC], br[BC];
    auto load_tiles = [&](int k0) {
#pragma unroll
        for (int p = 0; p < AC; ++p) {
            int c = tid + p * 256;
            int row = c >> 2, qq = c & 3;
            ar[p] = *(const short8*)&A[(size_t)(m0 + row) * K + k0 + qq * 8];
        }
#pragma unroll
        for (int p = 0; p < BC; ++p) {
            int c = tid + p * 256;
            int row = c >> 2, qq = c & 3;
            br[p] = *(const short8*)&W[(size_t)(n0 + row) * K + k0 + qq * 8];
        }
    };

    load_tiles(0);
    for (int k0 = 0; k0 < K; k0 += 32) {
#pragma unroll
        for (int p = 0; p < AC; ++p) {
            int c = tid + p * 256;
            *(short8*)&As[(c >> 2) * 40 + (c & 3) * 8] = ar[p];
        }
#pragma unroll
        for (int p = 0; p < BC; ++p) {
            int c = tid + p * 256;
            *(short8*)&Bs[(c >> 2) * 40 + (c & 3) * 8] = br[p];
        }
        __syncthreads();
        if (k0 + 32 < K) load_tiles(k0 + 32);

        short8 af[MI], bfr[NI];
#pragma unroll
        for (int i = 0; i < MI; ++i)
            af[i] = *(const short8*)&As[(wm * MI * 16 + i * 16 + lm) * 40 + q * 8];
#pragma unroll
        for (int j = 0; j < NI; ++j)
            bfr[j] = *(const short8*)&Bs[(wn * NI * 16 + j * 16 + lm) * 40 + q * 8];
#pragma unroll
        for (int i = 0; i < MI; ++i)
#pragma unroll
            for (int j = 0; j < NI; ++j)
                acc[i][j] = __builtin_amdgcn_mfma_f32_16x16x32_bf16(af[i], bfr[j], acc[i][j], 0, 0, 0);
        __syncthreads();
    }

    float bv[NI];
#pragma unroll
    for (int j = 0; j < NI; ++j)
        bv[j] = bias[n0 + wn * NI * 16 + j * 16 + lm];
#pragma unroll
    for (int i = 0; i < MI; ++i) {
#pragma unroll
        for (int j = 0; j < NI; ++j) {
            int col = n0 + wn * NI * 16 + j * 16 + lm;
#pragma unroll
            for (int r = 0; r < 4; ++r) {
                int row = m0 + wm * MI * 16 + i * 16 + q * 4 + r;
                C[(size_t)row * N + col] = acc[i][j][r] + bv[j];
            }
        }
    }
}

// ---------------------------------------------------------------------------
// Fused GRU step: 64 blocks x 16 gate-columns. Block owns the (r,z,n) triple
// for its columns -> gates finish in-register, no GH buffer.
// C[64 x 48] = h[64x1024] @ w_hh_sub[48x1024]^T, BK=64, then pointwise.
// hb ping-pong: reads hbin, writes hbout (other blocks still read hbin).
// ---------------------------------------------------------------------------
__global__ __launch_bounds__(256) void gru_step(
    const ushort* __restrict__ hbin, const ushort* __restrict__ wb,
    const float* __restrict__ bhh, const float* __restrict__ GI,
    float* __restrict__ h, ushort* __restrict__ hbout,
    ushort* __restrict__ hsb, float* __restrict__ hlast, int t) {
    __shared__ ushort Hs[64 * 72];
    __shared__ ushort Ws[48 * 72];
    const int tid = threadIdx.x;
    const int wm = tid >> 6, lane = tid & 63;
    const int lm = lane & 15, q = lane >> 4;
    const int j0 = blockIdx.x * 16;

    floatx4 accr = {0.f, 0.f, 0.f, 0.f};
    floatx4 accz = {0.f, 0.f, 0.f, 0.f};
    floatx4 accn = {0.f, 0.f, 0.f, 0.f};

    // staging chunk maps (16B chunks of 8 bf16):
    // Hs: 512 chunks, row=c>>3 (batch), q8=c&7. c in {tid, tid+256}.
    // Ws: 384 chunks, n_local=c>>3 (0..47), gate=n_local>>4, col j0+(n_local&15).
    short8 ar0, ar1, br0, br1;
    auto load_tiles = [&](int k0) {
        {
            int c = tid;
            ar0 = *(const short8*)&hbin[(size_t)(c >> 3) * H_DIM + k0 + (c & 7) * 8];
        }
        {
            int c = tid + 256;
            ar1 = *(const short8*)&hbin[(size_t)(c >> 3) * H_DIM + k0 + (c & 7) * 8];
        }
        {
            int c = tid;
            int nl = c >> 3;
            int grow = (nl >> 4) * H_DIM + j0 + (nl & 15);
            br0 = *(const short8*)&wb[(size_t)grow * H_DIM + k0 + (c & 7) * 8];
        }
        if (tid < 128) {
            int c = tid + 256;
            int nl = c >> 3;
            int grow = (nl >> 4) * H_DIM + j0 + (nl & 15);
            br1 = *(const short8*)&wb[(size_t)grow * H_DIM + k0 + (c & 7) * 8];
        }
    };

    load_tiles(0);
    for (int k0 = 0; k0 < H_DIM; k0 += 64) {
        {
            int c = tid;
            *(short8*)&Hs[(c >> 3) * 72 + (c & 7) * 8] = ar0;
        }
        {
            int c = tid + 256;
            *(short8*)&Hs[(c >> 3) * 72 + (c & 7) * 8] = ar1;
        }
        {
            int c = tid;
            *(short8*)&Ws[(c >> 3) * 72 + (c & 7) * 8] = br0;
        }
        if (tid < 128) {
            int c = tid + 256;
            *(short8*)&Ws[(c >> 3) * 72 + (c & 7) * 8] = br1;
        }
        __syncthreads();
        if (k0 + 64 < H_DIM) load_tiles(k0 + 64);
#pragma unroll
        for (int kk = 0; kk < 2; ++kk) {
            short8 af = *(const short8*)&Hs[(wm * 16 + lm) * 72 + kk * 32 + q * 8];
            short8 b0 = *(const short8*)&Ws[(lm) * 72 + kk * 32 + q * 8];
            short8 b1 = *(const short8*)&Ws[(16 + lm) * 72 + kk * 32 + q * 8];
            short8 b2 = *(const short8*)&Ws[(32 + lm) * 72 + kk * 32 + q * 8];
            accr = __builtin_amdgcn_mfma_f32_16x16x32_bf16(af, b0, accr, 0, 0, 0);
            accz = __builtin_amdgcn_mfma_f32_16x16x32_bf16(af, b1, accz, 0, 0, 0);
            accn = __builtin_amdgcn_mfma_f32_16x16x32_bf16(af, b2, accn, 0, 0, 0);
        }
        __syncthreads();
    }

    // epilogue: lane owns rows b = wm*16 + q*4 + r, column j = j0 + lm
    const int j = j0 + lm;
    const float bhr = bhh[j], bhz = bhh[H_DIM + j], bhn = bhh[2 * H_DIM + j];
#pragma unroll
    for (int r = 0; r < 4; ++r) {
        int b = wm * 16 + q * 4 + r;
        const float* gi = GI + (size_t)(t * B_SZ + b) * H3 + j;
        float ir = gi[0], iz = gi[H_DIM], in = gi[2 * H_DIM];
        float hr = accr[r] + bhr, hz = accz[r] + bhz, hn = accn[r] + bhn;
        float rg = fast_sigmoid(ir + hr);
        float z = fast_sigmoid(iz + hz);
        float ng = fast_tanh(in + rg * hn);
        size_t hi = (size_t)b * H_DIM + j;
        float hv = h[hi];
        float hnew = (1.f - z) * ng + z * hv;
        h[hi] = hnew;
        ushort h16 = f2b(hnew);
        hbout[hi] = h16;
        hsb[(size_t)t * B_SZ * H_DIM + hi] = h16;
        if (t == T_LEN - 1) hlast[hi] = hnew;
    }
}

// ---------------------------------------------------------------------------
// Additive-attention scores + softmax over S. Block tb = t*B + b
// (same-b blocks are 64 apart -> same XCD -> UK b-slice stays in L2).
// ---------------------------------------------------------------------------
__global__ __launch_bounds__(256) void attn_scores(const float* __restrict__ WQ,
                                                   const float* __restrict__ UK,
                                                   const float* __restrict__ va_w,
                                                   const float* __restrict__ va_b,
                                                   float* __restrict__ weights) {
    __shared__ float wq_s[H_DIM];
    __shared__ float va_s[H_DIM];
    __shared__ float sc[S_LEN];
    int tb = blockIdx.x;         // t*B + b
    int b = tb % B_SZ;
    int tid = threadIdx.x;
    for (int hh = tid; hh < H_DIM; hh += 256) {
        wq_s[hh] = WQ[(size_t)tb * H_DIM + hh];
        va_s[hh] = va_w[hh];
    }
    __syncthreads();
    int wave = tid / 64, lane = tid % 64;
    for (int s = wave; s < S_LEN; s += 4) {
        const float* uk = UK + ((size_t)b * S_LEN + s) * H_DIM;
        float acc = 0.f;
#pragma unroll
        for (int i = 0; i < H_DIM / 64; ++i) {
            int hh = i * 64 + lane;
            acc += fast_tanh(wq_s[hh] + uk[hh]) * va_s[hh];
        }
        for (int off = 32; off > 0; off >>= 1) acc += __shfl_down(acc, off);
        if (lane == 0) sc[s] = acc + va_b[0];
    }
    __syncthreads();
    if (tid < 64) {
        float v = (tid < S_LEN) ? sc[tid] : -INFINITY;
        float m = v;
        for (int off = 32; off > 0; off >>= 1) m = fmaxf(m, __shfl_down(m, off));
        m = __shfl(m, 0);
        float e = (tid < S_LEN) ? __expf(v - m) : 0.f;
        float sum = e;
        for (int off = 32; off > 0; off >>= 1) sum += __shfl_down(sum, off);
        sum = __shfl(sum, 0);
        if (tid < S_LEN) weights[(size_t)tb * S_LEN + tid] = e / sum;
    }
}

// ---------------------------------------------------------------------------
// context + log_softmax from bf16 keys. Block bt = t*64 + b (same-b same XCD).
// Thread owns 8 consecutive d's -> short8 key loads (16B/lane).
// Output written at [b, t, :] (b-major).
// ---------------------------------------------------------------------------
__global__ __launch_bounds__(256) void ctx_logsoftmax(const float* __restrict__ weights,
                                                      const ushort* __restrict__ keysb,
                                                      float* __restrict__ out) {
    __shared__ float w_s[S_LEN];
    __shared__ float wred[4];
    __shared__ float sred[4];
    int bt = blockIdx.x;        // t*64 + b
    int t = bt >> 6, b = bt & 63;
    int tid = threadIdx.x;
    if (tid < S_LEN) w_s[tid] = weights[((size_t)t * B_SZ + b) * S_LEN + tid];
    __syncthreads();

    float c[8];
#pragma unroll
    for (int i = 0; i < 8; ++i) c[i] = 0.f;
    const ushort* kb = keysb + (size_t)b * S_LEN * D2H + tid * 8;
    for (int s = 0; s < S_LEN; ++s) {
        float ws = w_s[s];
        short8 kv = *(const short8*)&kb[(size_t)s * D2H];
#pragma unroll
        for (int i = 0; i < 8; ++i) c[i] += ws * b2f((ushort)kv[i]);
    }

    int wave = tid / 64, lane = tid % 64;
    float m = c[0];
#pragma unroll
    for (int i = 1; i < 8; ++i) m = fmaxf(m, c[i]);
    for (int off = 32; off > 0; off >>= 1) m = fmaxf(m, __shfl_down(m, off));
    if (lane == 0) wred[wave] = m;
    __syncthreads();
    if (tid == 0) wred[0] = fmaxf(fmaxf(wred[0], wred[1]), fmaxf(wred[2], wred[3]));
    __syncthreads();
    m = wred[0];
    float sum = 0.f;
#pragma unroll
    for (int i = 0; i < 8; ++i) sum += __expf(c[i] - m);
    for (int off = 32; off > 0; off >>= 1) sum += __shfl_down(sum, off);
    if (lane == 0) sred[wave] = sum;
    __syncthreads();
    if (tid == 0) sred[0] = sred[0] + sred[1] + sred[2] + sred[3];
    __syncthreads();
    float lse = m + __logf(sred[0]);

    float* o = out + ((size_t)b * T_LEN + t) * D2H + tid * 8;
#pragma unroll
    for (int i = 0; i < 8; ++i) o[i] = c[i] - lse;
}

// ---------------------------------------------------------------------------
extern "C" void kernel_launch(void* const* d_in, const int* in_sizes, int n_in,
                              void* d_out, int out_size, void* d_ws, size_t ws_size,
                              hipStream_t stream) {
    const float* enc_out = (const float*)d_in[0];
    const float* hidden  = (const float*)d_in[1];
    const int*   target  = (const int*)d_in[2];
    const float* emb     = (const float*)d_in[3];
    const float* w_ih    = (const float*)d_in[4];
    const float* w_hh    = (const float*)d_in[5];
    const float* b_ih    = (const float*)d_in[6];
    const float* b_hh    = (const float*)d_in[7];
    const float* wa_w    = (const float*)d_in[8];
    const float* wa_b    = (const float*)d_in[9];
    const float* ua_w    = (const float*)d_in[10];
    const float* ua_b    = (const float*)d_in[11];
    const float* va_w    = (const float*)d_in[12];
    const float* va_b    = (const float*)d_in[13];
    float* out = (float*)d_out;

    const int TB = T_LEN * B_SZ;               // 640
    const int BS = B_SZ * S_LEN;               // 3200

    // workspace carve (16B-aligned chunks)
    char* p = (char*)d_ws;
    float*  GI    = (float*)p;  p += (size_t)TB * H3 * 4;
    float*  UK    = (float*)p;  p += (size_t)BS * H_DIM * 4;
    float*  WQ    = (float*)p;  p += (size_t)TB * H_DIM * 4;
    float*  h     = (float*)p;  p += (size_t)B_SZ * H_DIM * 4;
    float*  wts   = (float*)p;  p += (size_t)TB * S_LEN * 4;
    p = (char*)(((uintptr_t)p + 255) & ~(uintptr_t)255);
    ushort* keysb = (ushort*)p; p += (size_t)BS * D2H * 2;
    ushort* Xb    = (ushort*)p; p += (size_t)TB * E_DIM * 2;
    ushort* w_ihb = (ushort*)p; p += (size_t)H3 * E_DIM * 2;
    ushort* w_hhb = (ushort*)p; p += (size_t)H3 * H_DIM * 2;
    ushort* ua_wb = (ushort*)p; p += (size_t)H_DIM * D2H * 2;
    ushort* wa_wb = (ushort*)p; p += (size_t)H_DIM * H_DIM * 2;
    ushort* hb0   = (ushort*)p; p += (size_t)B_SZ * H_DIM * 2;
    ushort* hb1   = (ushort*)p; p += (size_t)B_SZ * H_DIM * 2;
    ushort* hsb   = (ushort*)p; p += (size_t)TB * H_DIM * 2;

    // fused prep
    prep<<<PB6, 256, 0, stream>>>(w_ih, w_ihb, w_hh, w_hhb, ua_w, ua_wb, wa_w, wa_wb,
                                  enc_out, keysb, target, emb, Xb, hidden, h, hb0);

    // GI = X @ w_ih^T + b_ih   [640, 3072], K=512, nbn=24
    gemm_bf16_nt<128, 2, 2><<<(TB / 128) * (H3 / 128), 256, 0, stream>>>(
        Xb, w_ihb, b_ih, GI, TB, H3, E_DIM, H3 / 128);
    // UK = keys @ ua_w^T + ua_b  [3200, 1024], K=2048, nbn=8
    gemm_bf16_nt<128, 2, 2><<<(BS / 128) * (H_DIM / 128), 256, 0, stream>>>(
        keysb, ua_wb, ua_b, UK, BS, H_DIM, D2H, H_DIM / 128);

    // fused GRU chain (ping-pong bf16 h)
    float* hlast = out + (size_t)B_SZ * T_LEN * D2H;
    for (int t = 0; t < T_LEN; ++t) {
        const ushort* hin = (t & 1) ? hb1 : hb0;
        ushort* hout = (t & 1) ? hb0 : hb1;
        gru_step<<<B_SZ, 256, 0, stream>>>(hin, w_hhb, b_hh, GI, h, hout, hsb, hlast, t);
    }

    // WQ = hs @ wa_w^T + wa_b  [640, 1024], K=1024, nbn=8
    gemm_bf16_nt<128, 2, 2><<<(TB / 128) * (H_DIM / 128), 256, 0, stream>>>(
        hsb, wa_wb, wa_b, WQ, TB, H_DIM, H_DIM, H_DIM / 128);

    // scores + softmax
    attn_scores<<<TB, 256, 0, stream>>>(WQ, UK, va_w, va_b, wts);

    // context + log_softmax -> out[0 : B*T*2H]
    ctx_logsoftmax<<<B_SZ * T_LEN, 256, 0, stream>>>(wts, keysb, out);
}

// Round 4
// 355.827 us; speedup vs baseline: 3.2425x; 1.0414x over previous
//
#include <hip/hip_runtime.h>
#include <math.h>

#define VOCAB 32000
#define E_DIM 512
#define H_DIM 1024
#define S_LEN 50
#define B_SZ 64
#define T_LEN 10
#define H3 (3 * H_DIM)
#define D2H (2 * H_DIM)

typedef __attribute__((ext_vector_type(8))) short short8;
typedef __attribute__((ext_vector_type(4))) float floatx4;

__device__ __forceinline__ ushort f2b(float f) {
    union { float f; uint32_t u; } x; x.f = f;
    uint32_t r = (x.u + 0x7fff + ((x.u >> 16) & 1)) >> 16;  // RNE
    return (ushort)r;
}
__device__ __forceinline__ float b2f(ushort u) {
    union { float f; uint32_t u; } x; x.u = ((uint32_t)u) << 16;
    return x.f;
}
__device__ __forceinline__ float fast_sigmoid(float x) {
    x = fminf(fmaxf(x, -30.f), 30.f);
    return 1.f / (1.f + __expf(-x));
}
__device__ __forceinline__ float fast_tanh(float x) {
    x = fminf(fmaxf(x, -15.f), 15.f);
    float e = __expf(2.f * x);
    return (e - 1.f) / (e + 1.f);
}

// ---------------------------------------------------------------------------
// Fused prep: 4 weight converts + keys gather + embed gather + h0 + barrier init
// ---------------------------------------------------------------------------
#define PB0 1536
#define PB1 (PB0 + 3072)
#define PB2 (PB1 + 2048)
#define PB3 (PB2 + 1024)
#define PB4 (PB3 + 3200)
#define PB5 (PB4 + 640)
#define PB6 (PB5 + 64)

__device__ __forceinline__ void cvt_chunk(const float* src, ushort* dst, int i) {
    float4 v = ((const float4*)src)[i];
    ushort4 o;
    o.x = f2b(v.x); o.y = f2b(v.y); o.z = f2b(v.z); o.w = f2b(v.w);
    ((ushort4*)dst)[i] = o;
}

__global__ __launch_bounds__(256) void prep(
    const float* __restrict__ w_ih, ushort* __restrict__ w_ihb,
    const float* __restrict__ w_hh, ushort* __restrict__ w_hhb,
    const float* __restrict__ ua_w, ushort* __restrict__ ua_wb,
    const float* __restrict__ wa_w, ushort* __restrict__ wa_wb,
    const float* __restrict__ enc_out, ushort* __restrict__ keysb,
    const int* __restrict__ target, const float* __restrict__ emb,
    ushort* __restrict__ Xb,
    const float* __restrict__ hidden, ushort* __restrict__ hb0,
    int* __restrict__ bar) {
    int bid = blockIdx.x, tid = threadIdx.x;
    if (bid == 0 && tid < 8) bar[tid] = 0;
    if (bid < PB0) {
        cvt_chunk(w_ih, w_ihb, bid * 256 + tid);
    } else if (bid < PB1) {
        cvt_chunk(w_hh, w_hhb, (bid - PB0) * 256 + tid);
    } else if (bid < PB2) {
        cvt_chunk(ua_w, ua_wb, (bid - PB1) * 256 + tid);
    } else if (bid < PB3) {
        cvt_chunk(wa_w, wa_wb, (bid - PB2) * 256 + tid);
    } else if (bid < PB4) {
        int bs = bid - PB3;                   // b*S + s
        int b = bs / S_LEN, s = bs % S_LEN;
        const float* src = enc_out + ((size_t)s * B_SZ + b) * D2H;
        ushort* dst = keysb + (size_t)bs * D2H;
#pragma unroll
        for (int p = 0; p < 2; ++p) {
            int i = tid + p * 256;
            float4 v = ((const float4*)src)[i];
            ushort4 o;
            o.x = f2b(v.x); o.y = f2b(v.y); o.z = f2b(v.z); o.w = f2b(v.w);
            ((ushort4*)dst)[i] = o;
        }
    } else if (bid < PB5) {
        int m = bid - PB4;                    // t*B + b
        int t = m / B_SZ, b = m % B_SZ;
        int idx = (t == 0) ? 0 : target[b * T_LEN + (t - 1)];
        if (tid < 128) {
            const float* src = emb + (size_t)idx * E_DIM;
            float4 v = ((const float4*)src)[tid];
            ushort4 o;
            o.x = f2b(v.x); o.y = f2b(v.y); o.z = f2b(v.z); o.w = f2b(v.w);
            ((ushort4*)(Xb + (size_t)m * E_DIM))[tid] = o;
        }
    } else {
        cvt_chunk(hidden, hb0, (bid - PB5) * 256 + tid);
    }
}

// ---------------------------------------------------------------------------
// bf16 MFMA GEMM: C = A[M,K] @ W[N,K]^T + bias. BM=64, BN=128, BK=64.
// 4 waves: wm=w>>1 (2), wn=w&1 (2); wave tile 32x64 (MI=2, NI=4).
// Staging: full 128B-line coalesced (8 lanes cover one row's 128B K-chunk).
// Two GEMMs merged per dispatch via GemmArgs pair (bid switch).
// Output f32 (Cf) or bf16 (C16) selected at runtime.
// ---------------------------------------------------------------------------
struct GemmArgs {
    const ushort* A; const ushort* W; const float* bias;
    float* Cf; ushort* C16;
    int M, N, K, nbn, nblk;
};

__global__ __launch_bounds__(256) void gemm_bf16(GemmArgs g0, GemmArgs g1) {
    const bool first = (int)blockIdx.x < g0.nblk;
    GemmArgs g = first ? g0 : g1;
    const int bid = first ? blockIdx.x : (blockIdx.x - g0.nblk);

    __shared__ ushort As[64 * 72];
    __shared__ ushort Bs[128 * 72];

    const int tid = threadIdx.x;
    const int w = tid >> 6, lane = tid & 63;
    const int lm = lane & 15, q = lane >> 4;
    const int wm = w >> 1, wn = w & 1;
    const int n0 = (bid % g.nbn) * 128;
    const int m0 = (bid / g.nbn) * 64;
    const int K = g.K;

    floatx4 acc[2][4];
#pragma unroll
    for (int i = 0; i < 2; ++i)
#pragma unroll
        for (int j = 0; j < 4; ++j)
            acc[i][j] = (floatx4){0.f, 0.f, 0.f, 0.f};

    short8 ar[2], br[4];
    auto load_tiles = [&](int k0) {
#pragma unroll
        for (int p = 0; p < 2; ++p) {
            int c = tid + p * 256;           // 512 A-chunks: row=c>>3, off=c&7
            ar[p] = *(const short8*)&g.A[(size_t)(m0 + (c >> 3)) * K + k0 + (c & 7) * 8];
        }
#pragma unroll
        for (int p = 0; p < 4; ++p) {
            int c = tid + p * 256;           // 1024 B-chunks
            br[p] = *(const short8*)&g.W[(size_t)(n0 + (c >> 3)) * K + k0 + (c & 7) * 8];
        }
    };

    load_tiles(0);
    for (int k0 = 0; k0 < K; k0 += 64) {
#pragma unroll
        for (int p = 0; p < 2; ++p) {
            int c = tid + p * 256;
            *(short8*)&As[(c >> 3) * 72 + (c & 7) * 8] = ar[p];
        }
#pragma unroll
        for (int p = 0; p < 4; ++p) {
            int c = tid + p * 256;
            *(short8*)&Bs[(c >> 3) * 72 + (c & 7) * 8] = br[p];
        }
        __syncthreads();
        if (k0 + 64 < K) load_tiles(k0 + 64);

#pragma unroll
        for (int kk = 0; kk < 2; ++kk) {
            short8 af[2], bf[4];
#pragma unroll
            for (int i = 0; i < 2; ++i)
                af[i] = *(const short8*)&As[(wm * 32 + i * 16 + lm) * 72 + kk * 32 + q * 8];
#pragma unroll
            for (int j = 0; j < 4; ++j)
                bf[j] = *(const short8*)&Bs[(wn * 64 + j * 16 + lm) * 72 + kk * 32 + q * 8];
#pragma unroll
            for (int i = 0; i < 2; ++i)
#pragma unroll
                for (int j = 0; j < 4; ++j)
                    acc[i][j] = __builtin_amdgcn_mfma_f32_16x16x32_bf16(af[i], bf[j], acc[i][j], 0, 0, 0);
        }
        __syncthreads();
    }

    float bv[4];
#pragma unroll
    for (int j = 0; j < 4; ++j)
        bv[j] = g.bias[n0 + wn * 64 + j * 16 + lm];
#pragma unroll
    for (int i = 0; i < 2; ++i) {
#pragma unroll
        for (int j = 0; j < 4; ++j) {
            int col = n0 + wn * 64 + j * 16 + lm;
#pragma unroll
            for (int r = 0; r < 4; ++r) {
                int row = m0 + wm * 32 + i * 16 + q * 4 + r;
                float v = acc[i][j][r] + bv[j];
                if (g.C16) g.C16[(size_t)row * g.N + col] = f2b(v);
                else       g.Cf[(size_t)row * g.N + col] = v;
            }
        }
    }
}

// ---------------------------------------------------------------------------
// Persistent GRU: 64 blocks, block owns 16 h-columns (48 w_hh rows).
// Inter-step device-scope grid barrier (64 blocks = 1/CU, co-resident).
// w_hh slice streamed L2->LDS (double-buffered); h read directly into
// A-fragments (wave-exclusive batch rows); f32 h kept in registers.
// ---------------------------------------------------------------------------
#define GRU_BLOCKS 64

__device__ __forceinline__ void grid_barrier(int* cnt, int* gen, int phase) {
    __syncthreads();
    if (threadIdx.x == 0) {
        __threadfence();
        if (atomicAdd(cnt, 1) == GRU_BLOCKS - 1) {
            atomicExch(cnt, 0);
            __threadfence();
            atomicExch(gen, phase + 1);
        } else {
            while (atomicAdd(gen, 0) <= phase) __builtin_amdgcn_s_sleep(8);
        }
        __threadfence();
    }
    __syncthreads();
}

__global__ __launch_bounds__(256) void gru_persistent(
    const ushort* __restrict__ w_hhb, const float* __restrict__ bhh,
    const float* __restrict__ GI, const float* __restrict__ hidden,
    ushort* __restrict__ hb0, ushort* __restrict__ hb1,
    ushort* __restrict__ hsb, float* __restrict__ outTail,
    int* __restrict__ bar) {
    __shared__ ushort Ws[2][48 * 136];   // 48 rows x 128 k, stride 136 (16B-aligned)
    const int tid = threadIdx.x;
    const int w = tid >> 6, lane = tid & 63;
    const int lm = lane & 15, q = lane >> 4;
    const int j0 = blockIdx.x * 16;
    const int j = j0 + lm;

    const float bhr = bhh[j], bhz = bhh[H_DIM + j], bhn = bhh[2 * H_DIM + j];

    // f32 h for owned elements: rows w*16+q*4+r, col j
    float hf[4];
#pragma unroll
    for (int r = 0; r < 4; ++r)
        hf[r] = hidden[(size_t)(w * 16 + q * 4 + r) * H_DIM + j];

    short8 wr[3];
    auto stage_regs = [&](int kbase) {
#pragma unroll
        for (int p = 0; p < 3; ++p) {
            int c = tid + p * 256;               // 768 chunks: row=c>>4, off=c&15
            int row = c >> 4, off = c & 15;
            int grow = (row >> 4) * H_DIM + j0 + (row & 15);
            wr[p] = *(const short8*)&w_hhb[(size_t)grow * H_DIM + kbase + off * 8];
        }
    };
    auto write_lds = [&](int buf) {
#pragma unroll
        for (int p = 0; p < 3; ++p) {
            int c = tid + p * 256;
            *(short8*)&Ws[buf][(c >> 4) * 136 + (c & 15) * 8] = wr[p];
        }
    };

    for (int t = 0; t < T_LEN; ++t) {
        const ushort* hin = (t & 1) ? hb1 : hb0;
        ushort* hout = (t & 1) ? hb0 : hb1;

        // prefetch GI (epilogue operands) early
        float ir[4], iz[4], inn[4];
#pragma unroll
        for (int r = 0; r < 4; ++r) {
            const float* gi = GI + (size_t)(t * B_SZ + w * 16 + q * 4 + r) * H3 + j;
            ir[r] = gi[0]; iz[r] = gi[H_DIM]; inn[r] = gi[2 * H_DIM];
        }

        floatx4 accr = {0.f, 0.f, 0.f, 0.f};
        floatx4 accz = {0.f, 0.f, 0.f, 0.f};
        floatx4 accn = {0.f, 0.f, 0.f, 0.f};

        stage_regs(0);
        write_lds(0);
        const ushort* arow = hin + (size_t)(w * 16 + lm) * H_DIM + q * 8;

        for (int it = 0; it < 8; ++it) {         // K=1024, BK=128
            __syncthreads();
            if (it < 7) stage_regs((it + 1) * 128);
            short8 af[4];
#pragma unroll
            for (int kk = 0; kk < 4; ++kk)
                af[kk] = *(const short8*)&arow[it * 128 + kk * 32];
            const int buf = it & 1;
#pragma unroll
            for (int kk = 0; kk < 4; ++kk) {
                short8 b0 = *(const short8*)&Ws[buf][(lm) * 136 + kk * 32 + q * 8];
                short8 b1 = *(const short8*)&Ws[buf][(16 + lm) * 136 + kk * 32 + q * 8];
                short8 b2 = *(const short8*)&Ws[buf][(32 + lm) * 136 + kk * 32 + q * 8];
                accr = __builtin_amdgcn_mfma_f32_16x16x32_bf16(af[kk], b0, accr, 0, 0, 0);
                accz = __builtin_amdgcn_mfma_f32_16x16x32_bf16(af[kk], b1, accz, 0, 0, 0);
                accn = __builtin_amdgcn_mfma_f32_16x16x32_bf16(af[kk], b2, accn, 0, 0, 0);
            }
            if (it < 7) write_lds(buf ^ 1);
        }

        // epilogue
#pragma unroll
        for (int r = 0; r < 4; ++r) {
            int b = w * 16 + q * 4 + r;
            float rg = fast_sigmoid(ir[r] + accr[r] + bhr);
            float z  = fast_sigmoid(iz[r] + accz[r] + bhz);
            float ng = fast_tanh(inn[r] + rg * (accn[r] + bhn));
            float hnew = (1.f - z) * ng + z * hf[r];
            hf[r] = hnew;
            size_t hi = (size_t)b * H_DIM + j;
            ushort h16 = f2b(hnew);
            hout[hi] = h16;
            hsb[(size_t)t * B_SZ * H_DIM + hi] = h16;
            if (t == T_LEN - 1) outTail[hi] = hnew;
        }

        if (t < T_LEN - 1) grid_barrier(&bar[0], &bar[1], t);
    }
}

// ---------------------------------------------------------------------------
// Fused attention: scores + softmax + context + log_softmax.
// Block bt = t*64 + b (same-b blocks hit same XCD L2 slice of UK/keys).
// ---------------------------------------------------------------------------
__global__ __launch_bounds__(256) void attn_ctx(
    const ushort* __restrict__ WQ16, const ushort* __restrict__ UK16,
    const float* __restrict__ va_w, const float* __restrict__ va_b,
    const ushort* __restrict__ keysb, float* __restrict__ out) {
    __shared__ float wq_s[H_DIM];
    __shared__ float va_s[H_DIM];
    __shared__ float sc[S_LEN];
    __shared__ float wred[4];
    __shared__ float sred[4];
    const int bt = blockIdx.x;       // t*64 + b
    const int t = bt >> 6, b = bt & 63;
    const int tid = threadIdx.x;
    const int wave = tid >> 6, lane = tid & 63;

    for (int hh = tid; hh < H_DIM; hh += 256) {
        wq_s[hh] = b2f(WQ16[(size_t)(t * B_SZ + b) * H_DIM + hh]);
        va_s[hh] = va_w[hh];
    }
    __syncthreads();

    // scores
    for (int s = wave; s < S_LEN; s += 4) {
        const ushort* uk = UK16 + ((size_t)b * S_LEN + s) * H_DIM + lane * 16;
        short8 u0 = *(const short8*)&uk[0];
        short8 u1 = *(const short8*)&uk[8];
        float acc = 0.f;
        const int h0 = lane * 16;
#pragma unroll
        for (int i = 0; i < 8; ++i)
            acc += fast_tanh(wq_s[h0 + i] + b2f((ushort)u0[i])) * va_s[h0 + i];
#pragma unroll
        for (int i = 0; i < 8; ++i)
            acc += fast_tanh(wq_s[h0 + 8 + i] + b2f((ushort)u1[i])) * va_s[h0 + 8 + i];
        for (int off = 32; off > 0; off >>= 1) acc += __shfl_down(acc, off);
        if (lane == 0) sc[s] = acc + va_b[0];
    }
    __syncthreads();

    // softmax over S (one wave)
    if (tid < 64) {
        float v = (tid < S_LEN) ? sc[tid] : -INFINITY;
        float m = v;
        for (int off = 32; off > 0; off >>= 1) m = fmaxf(m, __shfl_down(m, off));
        m = __shfl(m, 0);
        float e = (tid < S_LEN) ? __expf(v - m) : 0.f;
        float sum = e;
        for (int off = 32; off > 0; off >>= 1) sum += __shfl_down(sum, off);
        sum = __shfl(sum, 0);
        if (tid < S_LEN) sc[tid] = e / sum;
    }
    __syncthreads();

    // context
    float c[8];
#pragma unroll
    for (int i = 0; i < 8; ++i) c[i] = 0.f;
    const ushort* kb = keysb + (size_t)b * S_LEN * D2H + tid * 8;
    for (int s = 0; s < S_LEN; ++s) {
        float ws = sc[s];
        short8 kv = *(const short8*)&kb[(size_t)s * D2H];
#pragma unroll
        for (int i = 0; i < 8; ++i) c[i] += ws * b2f((ushort)kv[i]);
    }

    // log_softmax over 2H
    float m = c[0];
#pragma unroll
    for (int i = 1; i < 8; ++i) m = fmaxf(m, c[i]);
    for (int off = 32; off > 0; off >>= 1) m = fmaxf(m, __shfl_down(m, off));
    if (lane == 0) wred[wave] = m;
    __syncthreads();
    if (tid == 0) wred[0] = fmaxf(fmaxf(wred[0], wred[1]), fmaxf(wred[2], wred[3]));
    __syncthreads();
    m = wred[0];
    float sum = 0.f;
#pragma unroll
    for (int i = 0; i < 8; ++i) sum += __expf(c[i] - m);
    for (int off = 32; off > 0; off >>= 1) sum += __shfl_down(sum, off);
    if (lane == 0) sred[wave] = sum;
    __syncthreads();
    if (tid == 0) sred[0] = sred[0] + sred[1] + sred[2] + sred[3];
    __syncthreads();
    float lse = m + __logf(sred[0]);

    float* o = out + ((size_t)b * T_LEN + t) * D2H + tid * 8;
#pragma unroll
    for (int i = 0; i < 8; ++i) o[i] = c[i] - lse;
}

// ---------------------------------------------------------------------------
extern "C" void kernel_launch(void* const* d_in, const int* in_sizes, int n_in,
                              void* d_out, int out_size, void* d_ws, size_t ws_size,
                              hipStream_t stream) {
    const float* enc_out = (const float*)d_in[0];
    const float* hidden  = (const float*)d_in[1];
    const int*   target  = (const int*)d_in[2];
    const float* emb     = (const float*)d_in[3];
    const float* w_ih    = (const float*)d_in[4];
    const float* w_hh    = (const float*)d_in[5];
    const float* b_ih    = (const float*)d_in[6];
    const float* b_hh    = (const float*)d_in[7];
    const float* wa_w    = (const float*)d_in[8];
    const float* wa_b    = (const float*)d_in[9];
    const float* ua_w    = (const float*)d_in[10];
    const float* ua_b    = (const float*)d_in[11];
    const float* va_w    = (const float*)d_in[12];
    const float* va_b    = (const float*)d_in[13];
    float* out = (float*)d_out;

    const int TB = T_LEN * B_SZ;               // 640
    const int BS = B_SZ * S_LEN;               // 3200

    // workspace carve
    char* p = (char*)d_ws;
    int*    bar   = (int*)p;    p += 256;
    float*  GI    = (float*)p;  p += (size_t)TB * H3 * 4;
    p = (char*)(((uintptr_t)p + 255) & ~(uintptr_t)255);
    ushort* keysb = (ushort*)p; p += (size_t)BS * D2H * 2;
    ushort* Xb    = (ushort*)p; p += (size_t)TB * E_DIM * 2;
    ushort* w_ihb = (ushort*)p; p += (size_t)H3 * E_DIM * 2;
    ushort* w_hhb = (ushort*)p; p += (size_t)H3 * H_DIM * 2;
    ushort* ua_wb = (ushort*)p; p += (size_t)H_DIM * D2H * 2;
    ushort* wa_wb = (ushort*)p; p += (size_t)H_DIM * H_DIM * 2;
    ushort* hb0   = (ushort*)p; p += (size_t)B_SZ * H_DIM * 2;
    ushort* hb1   = (ushort*)p; p += (size_t)B_SZ * H_DIM * 2;
    ushort* hsb   = (ushort*)p; p += (size_t)TB * H_DIM * 2;
    ushort* UK16  = (ushort*)p; p += (size_t)BS * H_DIM * 2;
    ushort* WQ16  = (ushort*)p; p += (size_t)TB * H_DIM * 2;

    // prep
    prep<<<PB6, 256, 0, stream>>>(w_ih, w_ihb, w_hh, w_hhb, ua_w, ua_wb, wa_w, wa_wb,
                                  enc_out, keysb, target, emb, Xb, hidden, hb0, bar);

    // merged UK + GI GEMMs
    GemmArgs guk = { keysb, ua_wb, ua_b, nullptr, UK16,
                     BS, H_DIM, D2H, H_DIM / 128, (BS / 64) * (H_DIM / 128) };       // 400
    GemmArgs ggi = { Xb, w_ihb, b_ih, GI, nullptr,
                     TB, H3, E_DIM, H3 / 128, (TB / 64) * (H3 / 128) };              // 240
    gemm_bf16<<<guk.nblk + ggi.nblk, 256, 0, stream>>>(guk, ggi);

    // persistent GRU (writes hsb + h_last f32 tail)
    float* outTail = out + (size_t)B_SZ * T_LEN * D2H;
    gru_persistent<<<GRU_BLOCKS, 256, 0, stream>>>(w_hhb, b_hh, GI, hidden,
                                                   hb0, hb1, hsb, outTail, bar);

    // WQ = hs @ wa_w^T + wa_b  -> bf16
    GemmArgs gwq = { hsb, wa_wb, wa_b, nullptr, WQ16,
                     TB, H_DIM, H_DIM, H_DIM / 128, (TB / 64) * (H_DIM / 128) };     // 80
    gemm_bf16<<<gwq.nblk, 256, 0, stream>>>(gwq, gwq);

    // fused attention + context + log_softmax
    attn_ctx<<<B_SZ * T_LEN, 256, 0, stream>>>(WQ16, UK16, va_w, va_b, keysb, out);
}

// Round 5
// 348.058 us; speedup vs baseline: 3.3148x; 1.0223x over previous
//
#include <hip/hip_runtime.h>
#include <math.h>

#define VOCAB 32000
#define E_DIM 512
#define H_DIM 1024
#define S_LEN 50
#define B_SZ 64
#define T_LEN 10
#define H3 (3 * H_DIM)
#define D2H (2 * H_DIM)

typedef __attribute__((ext_vector_type(8))) short short8;
typedef __attribute__((ext_vector_type(4))) float floatx4;

__device__ __forceinline__ ushort f2b(float f) {
    union { float f; uint32_t u; } x; x.f = f;
    uint32_t r = (x.u + 0x7fff + ((x.u >> 16) & 1)) >> 16;  // RNE
    return (ushort)r;
}
__device__ __forceinline__ float b2f(ushort u) {
    union { float f; uint32_t u; } x; x.u = ((uint32_t)u) << 16;
    return x.f;
}
__device__ __forceinline__ float fast_sigmoid(float x) {
    x = fminf(fmaxf(x, -30.f), 30.f);
    return 1.f / (1.f + __expf(-x));
}
__device__ __forceinline__ float fast_tanh(float x) {
    x = fminf(fmaxf(x, -15.f), 15.f);
    float e = __expf(2.f * x);
    return (e - 1.f) / (e + 1.f);
}

// ---------------------------------------------------------------------------
// Fused prep: 4 weight converts + keys gather + embed gather + h0 + barrier init
// ---------------------------------------------------------------------------
#define PB0 1536
#define PB1 (PB0 + 3072)
#define PB2 (PB1 + 2048)
#define PB3 (PB2 + 1024)
#define PB4 (PB3 + 3200)
#define PB5 (PB4 + 640)
#define PB6 (PB5 + 64)

__device__ __forceinline__ void cvt_chunk(const float* src, ushort* dst, int i) {
    float4 v = ((const float4*)src)[i];
    ushort4 o;
    o.x = f2b(v.x); o.y = f2b(v.y); o.z = f2b(v.z); o.w = f2b(v.w);
    ((ushort4*)dst)[i] = o;
}

__global__ __launch_bounds__(256) void prep(
    const float* __restrict__ w_ih, ushort* __restrict__ w_ihb,
    const float* __restrict__ w_hh, ushort* __restrict__ w_hhb,
    const float* __restrict__ ua_w, ushort* __restrict__ ua_wb,
    const float* __restrict__ wa_w, ushort* __restrict__ wa_wb,
    const float* __restrict__ enc_out, ushort* __restrict__ keysb,
    const int* __restrict__ target, const float* __restrict__ emb,
    ushort* __restrict__ Xb,
    const float* __restrict__ hidden, ushort* __restrict__ hb0,
    int* __restrict__ bar) {
    int bid = blockIdx.x, tid = threadIdx.x;
    if (bid == 0) {
        for (int i = tid; i < 4096; i += 256) bar[i] = 0;
    }
    if (bid < PB0) {
        cvt_chunk(w_ih, w_ihb, bid * 256 + tid);
    } else if (bid < PB1) {
        cvt_chunk(w_hh, w_hhb, (bid - PB0) * 256 + tid);
    } else if (bid < PB2) {
        cvt_chunk(ua_w, ua_wb, (bid - PB1) * 256 + tid);
    } else if (bid < PB3) {
        cvt_chunk(wa_w, wa_wb, (bid - PB2) * 256 + tid);
    } else if (bid < PB4) {
        int bs = bid - PB3;                   // b*S + s
        int b = bs / S_LEN, s = bs % S_LEN;
        const float* src = enc_out + ((size_t)s * B_SZ + b) * D2H;
        ushort* dst = keysb + (size_t)bs * D2H;
#pragma unroll
        for (int p = 0; p < 2; ++p) {
            int i = tid + p * 256;
            float4 v = ((const float4*)src)[i];
            ushort4 o;
            o.x = f2b(v.x); o.y = f2b(v.y); o.z = f2b(v.z); o.w = f2b(v.w);
            ((ushort4*)dst)[i] = o;
        }
    } else if (bid < PB5) {
        int m = bid - PB4;                    // t*B + b
        int t = m / B_SZ, b = m % B_SZ;
        int idx = (t == 0) ? 0 : target[b * T_LEN + (t - 1)];
        if (tid < 128) {
            const float* src = emb + (size_t)idx * E_DIM;
            float4 v = ((const float4*)src)[tid];
            ushort4 o;
            o.x = f2b(v.x); o.y = f2b(v.y); o.z = f2b(v.z); o.w = f2b(v.w);
            ((ushort4*)(Xb + (size_t)m * E_DIM))[tid] = o;
        }
    } else {
        cvt_chunk(hidden, hb0, (bid - PB5) * 256 + tid);
    }
}

// ---------------------------------------------------------------------------
// bf16 MFMA GEMM: C = A[M,K] @ W[N,K]^T + bias. BM=64, BN=128, BK=64.
// Two GEMMs merged per dispatch via GemmArgs pair (bid switch).
// ---------------------------------------------------------------------------
struct GemmArgs {
    const ushort* A; const ushort* W; const float* bias;
    float* Cf; ushort* C16;
    int M, N, K, nbn, nblk;
};

__global__ __launch_bounds__(256) void gemm_bf16(GemmArgs g0, GemmArgs g1) {
    const bool first = (int)blockIdx.x < g0.nblk;
    GemmArgs g = first ? g0 : g1;
    const int bid = first ? blockIdx.x : (blockIdx.x - g0.nblk);

    __shared__ ushort As[64 * 72];
    __shared__ ushort Bs[128 * 72];

    const int tid = threadIdx.x;
    const int w = tid >> 6, lane = tid & 63;
    const int lm = lane & 15, q = lane >> 4;
    const int wm = w >> 1, wn = w & 1;
    const int n0 = (bid % g.nbn) * 128;
    const int m0 = (bid / g.nbn) * 64;
    const int K = g.K;

    floatx4 acc[2][4];
#pragma unroll
    for (int i = 0; i < 2; ++i)
#pragma unroll
        for (int j = 0; j < 4; ++j)
            acc[i][j] = (floatx4){0.f, 0.f, 0.f, 0.f};

    short8 ar[2], br[4];
    auto load_tiles = [&](int k0) {
#pragma unroll
        for (int p = 0; p < 2; ++p) {
            int c = tid + p * 256;
            ar[p] = *(const short8*)&g.A[(size_t)(m0 + (c >> 3)) * K + k0 + (c & 7) * 8];
        }
#pragma unroll
        for (int p = 0; p < 4; ++p) {
            int c = tid + p * 256;
            br[p] = *(const short8*)&g.W[(size_t)(n0 + (c >> 3)) * K + k0 + (c & 7) * 8];
        }
    };

    load_tiles(0);
    for (int k0 = 0; k0 < K; k0 += 64) {
#pragma unroll
        for (int p = 0; p < 2; ++p) {
            int c = tid + p * 256;
            *(short8*)&As[(c >> 3) * 72 + (c & 7) * 8] = ar[p];
        }
#pragma unroll
        for (int p = 0; p < 4; ++p) {
            int c = tid + p * 256;
            *(short8*)&Bs[(c >> 3) * 72 + (c & 7) * 8] = br[p];
        }
        __syncthreads();
        if (k0 + 64 < K) load_tiles(k0 + 64);

#pragma unroll
        for (int kk = 0; kk < 2; ++kk) {
            short8 af[2], bf[4];
#pragma unroll
            for (int i = 0; i < 2; ++i)
                af[i] = *(const short8*)&As[(wm * 32 + i * 16 + lm) * 72 + kk * 32 + q * 8];
#pragma unroll
            for (int j = 0; j < 4; ++j)
                bf[j] = *(const short8*)&Bs[(wn * 64 + j * 16 + lm) * 72 + kk * 32 + q * 8];
#pragma unroll
            for (int i = 0; i < 2; ++i)
#pragma unroll
                for (int j = 0; j < 4; ++j)
                    acc[i][j] = __builtin_amdgcn_mfma_f32_16x16x32_bf16(af[i], bf[j], acc[i][j], 0, 0, 0);
        }
        __syncthreads();
    }

    float bv[4];
#pragma unroll
    for (int j = 0; j < 4; ++j)
        bv[j] = g.bias[n0 + wn * 64 + j * 16 + lm];
#pragma unroll
    for (int i = 0; i < 2; ++i) {
#pragma unroll
        for (int j = 0; j < 4; ++j) {
            int col = n0 + wn * 64 + j * 16 + lm;
#pragma unroll
            for (int r = 0; r < 4; ++r) {
                int row = m0 + wm * 32 + i * 16 + q * 4 + r;
                float v = acc[i][j][r] + bv[j];
                if (g.C16) g.C16[(size_t)row * g.N + col] = f2b(v);
                else       g.Cf[(size_t)row * g.N + col] = v;
            }
        }
    }
}

// ---------------------------------------------------------------------------
// Persistent GRU v2: 64 blocks (1/CU), block owns 16 h-columns.
// w_hh slice (48 rows x 1024 = 97 KB) loaded into LDS ONCE; steps have no
// intra-step __syncthreads. Inter-step barrier: phase-indexed hierarchical
// arrival (8 sub-counters -> master) + load-only polling (no RMW storm).
// bar layout (ints): sub[t*8+g] @ (t*8+g)*32 ; master[t] @ 2560+t*32 ; gen @ 3040
// ---------------------------------------------------------------------------
#define GRU_BLOCKS 64
#define WS_STRIDE 1032   // elements; 2064B row stride -> 2-way max bank alias (free)

__device__ __forceinline__ void grid_barrier(int* __restrict__ bar, int t, int bid) {
    __syncthreads();
    if (threadIdx.x == 0) {
        __threadfence();
        int g = bid & 7;
        int sub = __hip_atomic_fetch_add(&bar[(t * 8 + g) * 32], 1,
                                         __ATOMIC_ACQ_REL, __HIP_MEMORY_SCOPE_AGENT);
        if (sub == 7) {
            int m = __hip_atomic_fetch_add(&bar[2560 + t * 32], 1,
                                           __ATOMIC_ACQ_REL, __HIP_MEMORY_SCOPE_AGENT);
            if (m == 7)
                __hip_atomic_store(&bar[3040], t + 1,
                                   __ATOMIC_RELEASE, __HIP_MEMORY_SCOPE_AGENT);
        }
        while (__hip_atomic_load(&bar[3040], __ATOMIC_ACQUIRE,
                                 __HIP_MEMORY_SCOPE_AGENT) <= t)
            __builtin_amdgcn_s_sleep(2);
        __threadfence();
    }
    __syncthreads();
}

__global__ __launch_bounds__(256) void gru_persistent(
    const ushort* __restrict__ w_hhb, const float* __restrict__ bhh,
    const float* __restrict__ GI, const float* __restrict__ hidden,
    ushort* __restrict__ hb0, ushort* __restrict__ hb1,
    ushort* __restrict__ hsb, float* __restrict__ outTail,
    int* __restrict__ bar) {
    __shared__ ushort Ws[48 * WS_STRIDE];   // 97 KB, persistent across steps
    const int tid = threadIdx.x;
    const int w = tid >> 6, lane = tid & 63;
    const int lm = lane & 15, q = lane >> 4;
    const int bid = blockIdx.x;
    const int j0 = bid * 16;
    const int j = j0 + lm;

    // one-time: stage w_hh slice into LDS (rows nl=gate*16+col -> global row)
#pragma unroll
    for (int p = 0; p < 24; ++p) {
        int c = tid + p * 256;                // 6144 chunks: row=c>>7, off=c&127
        int row = c >> 7, off = c & 127;
        int grow = (row >> 4) * H_DIM + j0 + (row & 15);
        *(short8*)&Ws[row * WS_STRIDE + off * 8] =
            *(const short8*)&w_hhb[(size_t)grow * H_DIM + off * 8];
    }

    const float bhr = bhh[j], bhz = bhh[H_DIM + j], bhn = bhh[2 * H_DIM + j];

    float hf[4];
#pragma unroll
    for (int r = 0; r < 4; ++r)
        hf[r] = hidden[(size_t)(w * 16 + q * 4 + r) * H_DIM + j];

    __syncthreads();   // Ws ready

    for (int t = 0; t < T_LEN; ++t) {
        const ushort* hin = (t & 1) ? hb1 : hb0;
        ushort* hout = (t & 1) ? hb0 : hb1;

        // prefetch GI (epilogue operands)
        float ir[4], iz[4], inn[4];
#pragma unroll
        for (int r = 0; r < 4; ++r) {
            const float* gi = GI + (size_t)(t * B_SZ + w * 16 + q * 4 + r) * H3 + j;
            ir[r] = gi[0]; iz[r] = gi[H_DIM]; inn[r] = gi[2 * H_DIM];
        }

        floatx4 accr = {0.f, 0.f, 0.f, 0.f};
        floatx4 accz = {0.f, 0.f, 0.f, 0.f};
        floatx4 accn = {0.f, 0.f, 0.f, 0.f};

        const ushort* arow = hin + (size_t)(w * 16 + lm) * H_DIM + q * 8;

        short8 af[4], afn[4];
#pragma unroll
        for (int kk = 0; kk < 4; ++kk)
            afn[kk] = *(const short8*)&arow[kk * 32];

#pragma unroll
        for (int it = 0; it < 8; ++it) {       // K=1024, 128 per iter
#pragma unroll
            for (int kk = 0; kk < 4; ++kk) af[kk] = afn[kk];
            if (it < 7) {
#pragma unroll
                for (int kk = 0; kk < 4; ++kk)
                    afn[kk] = *(const short8*)&arow[(it + 1) * 128 + kk * 32];
            }
#pragma unroll
            for (int kk = 0; kk < 4; ++kk) {
                const int ko = it * 128 + kk * 32 + q * 8;
                short8 b0 = *(const short8*)&Ws[(lm) * WS_STRIDE + ko];
                short8 b1 = *(const short8*)&Ws[(16 + lm) * WS_STRIDE + ko];
                short8 b2 = *(const short8*)&Ws[(32 + lm) * WS_STRIDE + ko];
                accr = __builtin_amdgcn_mfma_f32_16x16x32_bf16(af[kk], b0, accr, 0, 0, 0);
                accz = __builtin_amdgcn_mfma_f32_16x16x32_bf16(af[kk], b1, accz, 0, 0, 0);
                accn = __builtin_amdgcn_mfma_f32_16x16x32_bf16(af[kk], b2, accn, 0, 0, 0);
            }
        }

        // epilogue
#pragma unroll
        for (int r = 0; r < 4; ++r) {
            int b = w * 16 + q * 4 + r;
            float rg = fast_sigmoid(ir[r] + accr[r] + bhr);
            float z  = fast_sigmoid(iz[r] + accz[r] + bhz);
            float ng = fast_tanh(inn[r] + rg * (accn[r] + bhn));
            float hnew = (1.f - z) * ng + z * hf[r];
            hf[r] = hnew;
            size_t hi = (size_t)b * H_DIM + j;
            ushort h16 = f2b(hnew);
            hout[hi] = h16;
            hsb[(size_t)t * B_SZ * H_DIM + hi] = h16;
            if (t == T_LEN - 1) outTail[hi] = hnew;
        }

        if (t < T_LEN - 1) grid_barrier(bar, t, bid);
    }
}

// ---------------------------------------------------------------------------
// Fused attention: scores + softmax + context + log_softmax.
// ---------------------------------------------------------------------------
__global__ __launch_bounds__(256) void attn_ctx(
    const ushort* __restrict__ WQ16, const ushort* __restrict__ UK16,
    const float* __restrict__ va_w, const float* __restrict__ va_b,
    const ushort* __restrict__ keysb, float* __restrict__ out) {
    __shared__ float wq_s[H_DIM];
    __shared__ float va_s[H_DIM];
    __shared__ float sc[S_LEN];
    __shared__ float wred[4];
    __shared__ float sred[4];
    const int bt = blockIdx.x;       // t*64 + b
    const int t = bt >> 6, b = bt & 63;
    const int tid = threadIdx.x;
    const int wave = tid >> 6, lane = tid & 63;

    for (int hh = tid; hh < H_DIM; hh += 256) {
        wq_s[hh] = b2f(WQ16[(size_t)(t * B_SZ + b) * H_DIM + hh]);
        va_s[hh] = va_w[hh];
    }
    __syncthreads();

    for (int s = wave; s < S_LEN; s += 4) {
        const ushort* uk = UK16 + ((size_t)b * S_LEN + s) * H_DIM + lane * 16;
        short8 u0 = *(const short8*)&uk[0];
        short8 u1 = *(const short8*)&uk[8];
        float acc = 0.f;
        const int h0 = lane * 16;
#pragma unroll
        for (int i = 0; i < 8; ++i)
            acc += fast_tanh(wq_s[h0 + i] + b2f((ushort)u0[i])) * va_s[h0 + i];
#pragma unroll
        for (int i = 0; i < 8; ++i)
            acc += fast_tanh(wq_s[h0 + 8 + i] + b2f((ushort)u1[i])) * va_s[h0 + 8 + i];
        for (int off = 32; off > 0; off >>= 1) acc += __shfl_down(acc, off);
        if (lane == 0) sc[s] = acc + va_b[0];
    }
    __syncthreads();

    if (tid < 64) {
        float v = (tid < S_LEN) ? sc[tid] : -INFINITY;
        float m = v;
        for (int off = 32; off > 0; off >>= 1) m = fmaxf(m, __shfl_down(m, off));
        m = __shfl(m, 0);
        float e = (tid < S_LEN) ? __expf(v - m) : 0.f;
        float sum = e;
        for (int off = 32; off > 0; off >>= 1) sum += __shfl_down(sum, off);
        sum = __shfl(sum, 0);
        if (tid < S_LEN) sc[tid] = e / sum;
    }
    __syncthreads();

    float c[8];
#pragma unroll
    for (int i = 0; i < 8; ++i) c[i] = 0.f;
    const ushort* kb = keysb + (size_t)b * S_LEN * D2H + tid * 8;
    for (int s = 0; s < S_LEN; ++s) {
        float ws = sc[s];
        short8 kv = *(const short8*)&kb[(size_t)s * D2H];
#pragma unroll
        for (int i = 0; i < 8; ++i) c[i] += ws * b2f((ushort)kv[i]);
    }

    float m = c[0];
#pragma unroll
    for (int i = 1; i < 8; ++i) m = fmaxf(m, c[i]);
    for (int off = 32; off > 0; off >>= 1) m = fmaxf(m, __shfl_down(m, off));
    if (lane == 0) wred[wave] = m;
    __syncthreads();
    if (tid == 0) wred[0] = fmaxf(fmaxf(wred[0], wred[1]), fmaxf(wred[2], wred[3]));
    __syncthreads();
    m = wred[0];
    float sum = 0.f;
#pragma unroll
    for (int i = 0; i < 8; ++i) sum += __expf(c[i] - m);
    for (int off = 32; off > 0; off >>= 1) sum += __shfl_down(sum, off);
    if (lane == 0) sred[wave] = sum;
    __syncthreads();
    if (tid == 0) sred[0] = sred[0] + sred[1] + sred[2] + sred[3];
    __syncthreads();
    float lse = m + __logf(sred[0]);

    float* o = out + ((size_t)b * T_LEN + t) * D2H + tid * 8;
#pragma unroll
    for (int i = 0; i < 8; ++i) o[i] = c[i] - lse;
}

// ---------------------------------------------------------------------------
extern "C" void kernel_launch(void* const* d_in, const int* in_sizes, int n_in,
                              void* d_out, int out_size, void* d_ws, size_t ws_size,
                              hipStream_t stream) {
    const float* enc_out = (const float*)d_in[0];
    const float* hidden  = (const float*)d_in[1];
    const int*   target  = (const int*)d_in[2];
    const float* emb     = (const float*)d_in[3];
    const float* w_ih    = (const float*)d_in[4];
    const float* w_hh    = (const float*)d_in[5];
    const float* b_ih    = (const float*)d_in[6];
    const float* b_hh    = (const float*)d_in[7];
    const float* wa_w    = (const float*)d_in[8];
    const float* wa_b    = (const float*)d_in[9];
    const float* ua_w    = (const float*)d_in[10];
    const float* ua_b    = (const float*)d_in[11];
    const float* va_w    = (const float*)d_in[12];
    const float* va_b    = (const float*)d_in[13];
    float* out = (float*)d_out;

    const int TB = T_LEN * B_SZ;               // 640
    const int BS = B_SZ * S_LEN;               // 3200

    // workspace carve
    char* p = (char*)d_ws;
    int*    bar   = (int*)p;    p += 4096 * 4;
    float*  GI    = (float*)p;  p += (size_t)TB * H3 * 4;
    p = (char*)(((uintptr_t)p + 255) & ~(uintptr_t)255);
    ushort* keysb = (ushort*)p; p += (size_t)BS * D2H * 2;
    ushort* Xb    = (ushort*)p; p += (size_t)TB * E_DIM * 2;
    ushort* w_ihb = (ushort*)p; p += (size_t)H3 * E_DIM * 2;
    ushort* w_hhb = (ushort*)p; p += (size_t)H3 * H_DIM * 2;
    ushort* ua_wb = (ushort*)p; p += (size_t)H_DIM * D2H * 2;
    ushort* wa_wb = (ushort*)p; p += (size_t)H_DIM * H_DIM * 2;
    ushort* hb0   = (ushort*)p; p += (size_t)B_SZ * H_DIM * 2;
    ushort* hb1   = (ushort*)p; p += (size_t)B_SZ * H_DIM * 2;
    ushort* hsb   = (ushort*)p; p += (size_t)TB * H_DIM * 2;
    ushort* UK16  = (ushort*)p; p += (size_t)BS * H_DIM * 2;
    ushort* WQ16  = (ushort*)p; p += (size_t)TB * H_DIM * 2;

    // prep
    prep<<<PB6, 256, 0, stream>>>(w_ih, w_ihb, w_hh, w_hhb, ua_w, ua_wb, wa_w, wa_wb,
                                  enc_out, keysb, target, emb, Xb, hidden, hb0, bar);

    // merged UK + GI GEMMs
    GemmArgs guk = { keysb, ua_wb, ua_b, nullptr, UK16,
                     BS, H_DIM, D2H, H_DIM / 128, (BS / 64) * (H_DIM / 128) };
    GemmArgs ggi = { Xb, w_ihb, b_ih, GI, nullptr,
                     TB, H3, E_DIM, H3 / 128, (TB / 64) * (H3 / 128) };
    gemm_bf16<<<guk.nblk + ggi.nblk, 256, 0, stream>>>(guk, ggi);

    // persistent GRU (writes hsb + h_last f32 tail)
    float* outTail = out + (size_t)B_SZ * T_LEN * D2H;
    gru_persistent<<<GRU_BLOCKS, 256, 0, stream>>>(w_hhb, b_hh, GI, hidden,
                                                   hb0, hb1, hsb, outTail, bar);

    // WQ = hs @ wa_w^T + wa_b  -> bf16
    GemmArgs gwq = { hsb, wa_wb, wa_b, nullptr, WQ16,
                     TB, H_DIM, H_DIM, H_DIM / 128, (TB / 64) * (H_DIM / 128) };
    gemm_bf16<<<gwq.nblk, 256, 0, stream>>>(gwq, gwq);

    // fused attention + context + log_softmax
    attn_ctx<<<B_SZ * T_LEN, 256, 0, stream>>>(WQ16, UK16, va_w, va_b, keysb, out);
}